// Round 10
// baseline (417.964 us; speedup 1.0000x reference)
//
#include <hip/hip_runtime.h>
#include <math.h>

// ---- problem constants ----
#define B_      128
#define A_      24
#define N_      3072     // B_*A_
#define NLAYERS 4

// ---- workspace layout (float-element offsets) ----
// NOTE: each [3072][256] bf16 buffer = 786432 ushorts = 393216 float slots.
#define OFF_COND    0         // [128][512] f32                      (65536)
#define OFF_LATW    65536     // [4][128][256] f32                   (131072)
#define OFF_NFMIDH  196608    // [3072][256] bf16                    (393216)
#define OFF_AGGH    589824    // [3072][256] bf16                    (393216)
#define OFF_PARTIH  983040    // [3072][256] bf16 (incl. eb1+latW)   (393216)
#define OFF_PARTJH  1376256   // [3072][256] bf16                    (393216)
#define OFF_W1LATT  1769472   // [4][9][256] f32                     (9216)
#define OFF_PW1A    1778688   // [4][8][16][64][8] bf16              (131072)
#define OFF_PW1B    1909760   //                                     (131072)
#define OFF_PW1D    2040832   // [4][2][16][64][8] bf16              (32768)
#define OFF_PW2     2073600   // [4][8][16][64][8] bf16              (131072)
#define OFF_PWPROJ  2204672   // [8][16][64][8] bf16                 (32768)
#define OFF_PNW1    2237440   // [4][16][16][64][8] bf16             (262144)
#define OFF_PNW2    2499584   // [4][8][16][64][8] bf16              (131072)
#define OFF_PWEMB   2630656   // [4 ks][16 nt][64][8] bf16 (K pad)   (16384)
#define OFF_PWCOND  2647040   // [12 ks][32 nt][64][8] bf16 (K=384)  (98304)
#define OFF_PWTYPE  2745344   // [8 ks][7 nt][64][8] bf16 (N pad)    (14336)
// end 2759680 floats ~ 10.5 MiB

// output offsets (floats): types | lattice | coords | nf
#define OUT_TYPES  0
#define OUT_LATT   316416
#define OUT_COORD  317568
#define OUT_NF     326784

typedef __attribute__((ext_vector_type(8))) short bf16x8;
typedef __attribute__((ext_vector_type(4))) float f32x4;

__device__ __forceinline__ float silu_f(float x) { return x / (1.0f + __expf(-x)); }
__device__ __forceinline__ unsigned short f2bf(float x) {
    unsigned int u = __float_as_uint(x);
    return (unsigned short)((u + 0x7FFFu + ((u >> 16) & 1u)) >> 16);
}
__device__ __forceinline__ float bf2f(unsigned short h) {
    return __uint_as_float(((unsigned int)h) << 16);
}

// ---------------- weight packs ----------------
// generic pack: pack[((ks*NT + nt)*64 + lane)*8 + j] = W[k][n],
//   k = ks*32 + (lane>>4)*8 + j,  n = nt*16 + (lane&15)
__global__ void k_prep(const float* w_emb, const float* w_cond, const float* w_proj,
                       const float* ew1, const float* ew2, const float* nw1, const float* nw2,
                       const float* w_type, float* ws) {
    int idx = blockIdx.x * blockDim.x + threadIdx.x;
    unsigned short* pu = (unsigned short*)ws;
    int i = idx;
    if (i < 9216)   { int l = i / 2304, r = (i % 2304) / 256, h = i % 256;
                      ws[OFF_W1LATT + i] = ew1[((size_t)l * 256 + h) * 581 + 512 + r]; return; }        i -= 9216;
    if (i < 262144) { int l = i >> 16, r = i & 65535, ks = r >> 13, r2 = r & 8191,
                      nt = r2 >> 9, r3 = r2 & 511, lane = r3 >> 3, j = r3 & 7;
                      int k = ks * 32 + (lane >> 4) * 8 + j, n = nt * 16 + (lane & 15);
                      pu[(size_t)OFF_PW1A * 2 + i] = f2bf(ew1[((size_t)l * 256 + n) * 581 + k]); return; } i -= 262144;
    if (i < 262144) { int l = i >> 16, r = i & 65535, ks = r >> 13, r2 = r & 8191,
                      nt = r2 >> 9, r3 = r2 & 511, lane = r3 >> 3, j = r3 & 7;
                      int k = ks * 32 + (lane >> 4) * 8 + j, n = nt * 16 + (lane & 15);
                      pu[(size_t)OFF_PW1B * 2 + i] = f2bf(ew1[((size_t)l * 256 + n) * 581 + 256 + k]); return; } i -= 262144;
    if (i < 65536)  { int l = i >> 14, r = i & 16383, ks = r >> 13, r2 = r & 8191,
                      nt = r2 >> 9, r3 = r2 & 511, lane = r3 >> 3, j = r3 & 7;
                      int kp = ks * 32 + (lane >> 4) * 8 + j, n = nt * 16 + (lane & 15);
                      float v = (kp < 60) ? ew1[((size_t)l * 256 + n) * 581 + 521 + kp] : 0.0f;
                      pu[(size_t)OFF_PW1D * 2 + i] = f2bf(v); return; }                                  i -= 65536;
    if (i < 262144) { int l = i >> 16, r = i & 65535, ks = r >> 13, r2 = r & 8191,
                      nt = r2 >> 9, r3 = r2 & 511, lane = r3 >> 3, j = r3 & 7;
                      int k = ks * 32 + (lane >> 4) * 8 + j, n = nt * 16 + (lane & 15);
                      pu[(size_t)OFF_PW2 * 2 + i] = f2bf(ew2[((size_t)l * 256 + n) * 256 + k]); return; } i -= 262144;
    if (i < 65536)  { int ks = i >> 13, r2 = i & 8191,
                      nt = r2 >> 9, r3 = r2 & 511, lane = r3 >> 3, j = r3 & 7;
                      int k = ks * 32 + (lane >> 4) * 8 + j, n = nt * 16 + (lane & 15);
                      pu[(size_t)OFF_PWPROJ * 2 + i] = f2bf(w_proj[(size_t)n * 256 + k]); return; }      i -= 65536;
    if (i < 524288) { int l = i >> 17, r = i & 131071, ks = r >> 13, r2 = r & 8191,
                      nt = r2 >> 9, r3 = r2 & 511, lane = r3 >> 3, j = r3 & 7;
                      int k = ks * 32 + (lane >> 4) * 8 + j, n = nt * 16 + (lane & 15);
                      pu[(size_t)OFF_PNW1 * 2 + i] = f2bf(nw1[((size_t)l * 256 + n) * 512 + k]); return; } i -= 524288;
    if (i < 262144) { int l = i >> 16, r = i & 65535, ks = r >> 13, r2 = r & 8191,
                      nt = r2 >> 9, r3 = r2 & 511, lane = r3 >> 3, j = r3 & 7;
                      int k = ks * 32 + (lane >> 4) * 8 + j, n = nt * 16 + (lane & 15);
                      pu[(size_t)OFF_PNW2 * 2 + i] = f2bf(nw2[((size_t)l * 256 + n) * 256 + k]); return; } i -= 262144;
    if (i < 32768)  { int ks = i >> 13, r2 = i & 8191,
                      nt = r2 >> 9, r3 = r2 & 511, lane = r3 >> 3, j = r3 & 7;
                      int k = ks * 32 + (lane >> 4) * 8 + j, n = nt * 16 + (lane & 15);
                      float v = (k < 103) ? w_emb[(size_t)n * 103 + k] : 0.0f;
                      pu[(size_t)OFF_PWEMB * 2 + i] = f2bf(v); return; }                                 i -= 32768;
    if (i < 196608) { int ks = i / 16384, r2 = i & 16383,
                      nt = r2 >> 9, r3 = r2 & 511, lane = r3 >> 3, j = r3 & 7;
                      int k = ks * 32 + (lane >> 4) * 8 + j, n = nt * 16 + (lane & 15);
                      pu[(size_t)OFF_PWCOND * 2 + i] = f2bf(w_cond[(size_t)n * 384 + k]); return; }      i -= 196608;
    { int ks = i / 3584, r2 = i % 3584,
      nt = r2 >> 9, r3 = r2 & 511, lane = r3 >> 3, j = r3 & 7;
      int k = ks * 32 + (lane >> 4) * 8 + j, a = nt * 16 + (lane & 15);
      float v = (a < 103) ? w_type[(size_t)a * 256 + k] : 0.0f;
      pu[(size_t)OFF_PWTYPE * 2 + i] = f2bf(v); }
}

// ---------------- setup: latips + latW + cond (MFMA), 8 blocks x 16 graphs ----------------
__global__ void __launch_bounds__(256) k_setup(const float* lat, const float* t_in, const float* tx,
                                               const float* b_cond, float* ws) {
    __shared__ __align__(16) unsigned short s_ct[16][392];
    __shared__ float s_lat[16][9];
    int tid = threadIdx.x, w = tid >> 6, ln = tid & 63;
    int l15 = ln & 15, g = ln >> 4;
    int g0 = blockIdx.x * 16;
    if (tid < 144) {
        int gl = tid / 9, r = tid % 9, ii = r / 3, kk = r % 3;
        const float* L = lat + (g0 + gl) * 9;
        s_lat[gl][r] = L[ii*3+0]*L[kk*3+0] + L[ii*3+1]*L[kk*3+1] + L[ii*3+2]*L[kk*3+2];
    }
    for (int idx = tid; idx < 16 * 384; idx += 256) {
        int row = idx / 384, k = idx % 384;
        float v = (k < 256) ? t_in[(size_t)(g0 + row) * 256 + k] : tx[(size_t)(g0 + row) * 128 + (k - 256)];
        s_ct[row][k] = f2bf(v);
    }
    __syncthreads();
    for (int idx = tid; idx < 16384; idx += 256) {
        int l = idx >> 12, gl = (idx >> 8) & 15, h = idx & 255;
        float a = 0.f;
#pragma unroll
        for (int r = 0; r < 9; r++) a += s_lat[gl][r] * ws[OFF_W1LATT + (l * 9 + r) * 256 + h];
        ws[OFF_LATW + (size_t)(l * 128 + g0 + gl) * 256 + h] = a;
    }
    const unsigned short* pc = (const unsigned short*)ws + (size_t)OFF_PWCOND * 2;
    f32x4 acc[8] = {};
    for (int ks = 0; ks < 12; ks++) {
        bf16x8 a = *(const bf16x8*)&s_ct[l15][ks * 32 + g * 8];
#pragma unroll
        for (int q = 0; q < 8; q++) {
            int nt = w * 8 + q;
            bf16x8 bf = *(const bf16x8*)&pc[((size_t)(ks * 32 + nt) * 64 + ln) * 8];
            acc[q] = __builtin_amdgcn_mfma_f32_16x16x32_bf16(a, bf, acc[q], 0, 0, 0);
        }
    }
#pragma unroll
    for (int q = 0; q < 8; q++) {
        int col = w * 128 + q * 16 + l15;
        float bc = b_cond[col];
#pragma unroll
        for (int r = 0; r < 4; r++) {
            int gg = g0 + 4 * g + r;
            ws[OFF_COND + (size_t)gg * 512 + col] = silu_f(acc[q][r] + bc);
        }
    }
}

// ---------------- fused node-MLP(l-1) [or embed] + FiLM(l) + PartI/PartJ(l) ----------------
// 512 threads / 8 waves; wave w owns N-tiles nt16 = 2w, 2w+1 (cols 32w..32w+31)
__global__ void __launch_bounds__(512) k_fnf(int l, const float* at, const float* b_emb,
                                             const float* nb1, const float* nb2,
                                             const float* b_proj, const float* film_g, const float* film_b,
                                             const float* eb1, float* ws) {
    __shared__ __align__(16) unsigned short s_in[16][536];
    __shared__ __align__(16) unsigned short s_h[16][264];
    __shared__ __align__(16) unsigned short s_a[16][264];
    __shared__ float s_nf[16][260];
    __shared__ float s_mu[16], s_rs[16];
    float (*s_c)[268] = (float(*)[268])&s_in[0][0];   // aliased over s_in (used after node phase)
    int tid = threadIdx.x, w = tid >> 6, ln = tid & 63;
    int l15 = ln & 15, g = ln >> 4;
    int n0 = blockIdx.x * 16;
    const unsigned short* wsu = (const unsigned short*)ws;
    unsigned short* wsw = (unsigned short*)ws;

    f32x4 accn[2] = {};
    if (l == 0) {
        // ---- embed: nf = at @ w_emb^T + b_emb ----
        for (int idx = tid; idx < 16 * 128; idx += 512) {
            int row = idx >> 7, k = idx & 127;
            s_in[row][k] = (k < 103) ? f2bf(at[(size_t)(n0 + row) * 103 + k]) : (unsigned short)0;
        }
        __syncthreads();
        const unsigned short* pe = wsu + (size_t)OFF_PWEMB * 2;
        for (int ks = 0; ks < 4; ks++) {
            bf16x8 a = *(const bf16x8*)&s_in[l15][ks * 32 + g * 8];
#pragma unroll
            for (int q = 0; q < 2; q++) {
                bf16x8 bf = *(const bf16x8*)&pe[((size_t)(ks * 16 + 2 * w + q) * 64 + ln) * 8];
                accn[q] = __builtin_amdgcn_mfma_f32_16x16x32_bf16(a, bf, accn[q], 0, 0, 0);
            }
        }
        __syncthreads();
#pragma unroll
        for (int q = 0; q < 2; q++) {
            int col = w * 32 + q * 16 + l15;
            float be = b_emb[col];
#pragma unroll
            for (int r = 0; r < 4; r++) {
                int row = 4 * g + r;
                float v = accn[q][r] + be;
                s_nf[row][col] = v;
                s_a[row][col] = f2bf(v);
            }
        }
    } else {
        // ---- node MLP of layer l-1 ----
        int lp = l - 1;
        const unsigned short* nfmidh = wsu + (size_t)OFF_NFMIDH * 2;
        const unsigned short* aggh   = wsu + (size_t)OFF_AGGH * 2;
        {
            int row = tid >> 5, c8 = tid & 31;
            *(uint4*)&s_in[row][c8 * 8]       = *(const uint4*)&nfmidh[(size_t)(n0 + row) * 256 + c8 * 8];
            *(uint4*)&s_in[row][256 + c8 * 8] = *(const uint4*)&aggh[(size_t)(n0 + row) * 256 + c8 * 8];
        }
        __syncthreads();
        const unsigned short* p1 = wsu + (size_t)OFF_PNW1 * 2 + (size_t)lp * 131072;
        f32x4 acc[2] = {};
        for (int ks = 0; ks < 16; ks++) {
            bf16x8 a = *(const bf16x8*)&s_in[l15][ks * 32 + g * 8];
#pragma unroll
            for (int q = 0; q < 2; q++) {
                bf16x8 bf = *(const bf16x8*)&p1[((size_t)(ks * 16 + 2 * w + q) * 64 + ln) * 8];
                acc[q] = __builtin_amdgcn_mfma_f32_16x16x32_bf16(a, bf, acc[q], 0, 0, 0);
            }
        }
#pragma unroll
        for (int q = 0; q < 2; q++) {
            int col = w * 32 + q * 16 + l15;
            float b1 = nb1[lp * 256 + col];
#pragma unroll
            for (int r = 0; r < 4; r++) s_h[4 * g + r][col] = f2bf(silu_f(acc[q][r] + b1));
        }
        __syncthreads();
        const unsigned short* p2 = wsu + (size_t)OFF_PNW2 * 2 + (size_t)lp * 65536;
        for (int ks = 0; ks < 8; ks++) {
            bf16x8 a = *(const bf16x8*)&s_h[l15][ks * 32 + g * 8];
#pragma unroll
            for (int q = 0; q < 2; q++) {
                bf16x8 bf = *(const bf16x8*)&p2[((size_t)(ks * 16 + 2 * w + q) * 64 + ln) * 8];
                accn[q] = __builtin_amdgcn_mfma_f32_16x16x32_bf16(a, bf, accn[q], 0, 0, 0);
            }
        }
#pragma unroll
        for (int q = 0; q < 2; q++) {
            int col = w * 32 + q * 16 + l15;
            float b2 = nb2[lp * 256 + col];
#pragma unroll
            for (int r = 0; r < 4; r++) {
                int row = 4 * g + r;
                float v = bf2f(s_in[row][col]) + silu_f(accn[q][r] + b2);
                s_nf[row][col] = v;
                s_a[row][col] = f2bf(v);
            }
        }
    }
    __syncthreads();
    // ---- proj GEMM: [16 x 256] @ [256 x 256] ----
    const unsigned short* pwp = wsu + (size_t)OFF_PWPROJ * 2;
    f32x4 accp[2] = {};
    for (int ks = 0; ks < 8; ks++) {
        bf16x8 a = *(const bf16x8*)&s_a[l15][ks * 32 + g * 8];
#pragma unroll
        for (int q = 0; q < 2; q++) {
            bf16x8 bf = *(const bf16x8*)&pwp[((size_t)(ks * 16 + 2 * w + q) * 64 + ln) * 8];
            accp[q] = __builtin_amdgcn_mfma_f32_16x16x32_bf16(a, bf, accp[q], 0, 0, 0);
        }
    }
    __syncthreads();  // s_in (node phase) fully read; s_c (alias) may be written
#pragma unroll
    for (int q = 0; q < 2; q++) {
        int col = w * 32 + q * 16 + l15;
        float bp = b_proj[col];
#pragma unroll
        for (int r = 0; r < 4; r++) s_c[4 * g + r][col] = accp[q][r] + bp;
    }
    __syncthreads();
    // ---- LN stats: wave w handles rows 2w, 2w+1 ----
    for (int r2 = 0; r2 < 2; r2++) {
        int row = w * 2 + r2;
        float s = 0.f, q = 0.f;
        for (int c = ln; c < 256; c += 64) { float v = s_c[row][c]; s += v; q += v * v; }
#pragma unroll
        for (int o = 1; o < 64; o <<= 1) { s += __shfl_xor(s, o); q += __shfl_xor(q, o); }
        if (ln == 0) {
            float mu = s * (1.0f / 256.0f);
            float var = q * (1.0f / 256.0f) - mu * mu;
            s_mu[row] = mu; s_rs[row] = rsqrtf(var + 1e-5f);
        }
    }
    __syncthreads();
    // ---- FiLM epilogue: col = tid&255, rows (tid>>8) + 2t ----
    {
        int col = tid & 255, rb = tid >> 8;
        float gg = film_g[col], bb = film_b[col];
        unsigned short* nfmidh = wsw + (size_t)OFF_NFMIDH * 2;
#pragma unroll
        for (int t = 0; t < 8; t++) {
            int row = rb + 2 * t;
            int n = n0 + row, b = n / 24;
            float sc = ws[OFF_COND + (size_t)b * 512 + col];
            float sh = ws[OFF_COND + (size_t)b * 512 + 256 + col];
            float yn = (s_c[row][col] - s_mu[row]) * s_rs[row] * gg + bb;
            float outv = s_nf[row][col] + silu_f(yn * sc + sh);
            unsigned short ob = f2bf(outv);
            nfmidh[(size_t)n * 256 + col] = ob;
            s_a[row][col] = ob;
        }
    }
    __syncthreads();
    // ---- PartI/PartJ GEMMs ----
    const unsigned short* pA = wsu + (size_t)OFF_PW1A * 2 + (size_t)l * 65536;
    const unsigned short* pB = wsu + (size_t)OFF_PW1B * 2 + (size_t)l * 65536;
    f32x4 aI[2] = {}, aJ[2] = {};
    for (int ks = 0; ks < 8; ks++) {
        bf16x8 a = *(const bf16x8*)&s_a[l15][ks * 32 + g * 8];
#pragma unroll
        for (int q = 0; q < 2; q++) {
            bf16x8 bi = *(const bf16x8*)&pA[((size_t)(ks * 16 + 2 * w + q) * 64 + ln) * 8];
            bf16x8 bj = *(const bf16x8*)&pB[((size_t)(ks * 16 + 2 * w + q) * 64 + ln) * 8];
            aI[q] = __builtin_amdgcn_mfma_f32_16x16x32_bf16(a, bi, aI[q], 0, 0, 0);
            aJ[q] = __builtin_amdgcn_mfma_f32_16x16x32_bf16(a, bj, aJ[q], 0, 0, 0);
        }
    }
    unsigned short* partih = wsw + (size_t)OFF_PARTIH * 2;
    unsigned short* partjh = wsw + (size_t)OFF_PARTJH * 2;
#pragma unroll
    for (int q = 0; q < 2; q++) {
        int col = w * 32 + q * 16 + l15;
        float e1 = eb1[l * 256 + col];
#pragma unroll
        for (int r = 0; r < 4; r++) {
            int n = n0 + 4 * g + r;
            int gb = n / 24;
            float vi = aI[q][r] + e1 + ws[OFF_LATW + (size_t)(l * 128 + gb) * 256 + col];
            partih[(size_t)n * 256 + col] = f2bf(vi);
            partjh[(size_t)n * 256 + col] = f2bf(aJ[q][r]);
        }
    }
}

// ---------------- fused edge pipeline (R8 structure; Part reads from global; 6 blocks/CU) ----------------
__global__ void __launch_bounds__(256, 6) k_edge(int l, const float* frac, const float* eb2, float* ws) {
    __shared__ __align__(16) unsigned short s_u[48 * 256];   // ef1 (swizzled); demb aliased in first 6 KB
    __shared__ float s_fc[24][3];
    int tid = threadIdx.x, w = tid >> 6, ln = tid & 63;
    int l15 = ln & 15, g = ln >> 4;
    int b = blockIdx.x & 127, c = blockIdx.x >> 7;
    int i0 = c * 2, n0i = b * 24;
    const unsigned short* wsu = (const unsigned short*)ws;
    const unsigned short* partih = wsu + (size_t)OFF_PARTIH * 2;
    const unsigned short* partjh = wsu + (size_t)OFF_PARTJH * 2;

    for (int idx = tid; idx < 72; idx += 256) s_fc[idx / 3][idx % 3] = frac[b * 72 + idx];
    __syncthreads();
    // demb [48][64] bf16, swizzled chunk ^= row&7; k 60..63 zeroed
    for (int idx = tid; idx < 3072; idx += 256) {
        int row = idx >> 6, k = idx & 63;
        unsigned short v = 0;
        if (k < 60) {
            int kk = (k < 30) ? k : k - 30;
            int d = kk / 10, f = kk % 10;
            int hi = (row >= 24);
            int j = row - (hi ? 24 : 0);
            float fd = s_fc[j][d] - s_fc[i0 + hi][d];
            fd -= floorf(fd);
            float ang = fd * (6.283185307179586f * (float)f);
            v = f2bf((k < 30) ? __sinf(ang) : __cosf(ang));
        }
        s_u[(row << 6) + (((k >> 3) ^ (row & 7)) << 3) + (k & 7)] = v;
    }
    // PartI values into registers (8 scalar reads, L2-resident), issued before GEMM1
    float pIv[2][4];
#pragma unroll
    for (int hi = 0; hi < 2; hi++)
#pragma unroll
        for (int nt = 0; nt < 4; nt++)
            pIv[hi][nt] = bf2f(partih[(size_t)(n0i + i0 + hi) * 256 + w * 64 + nt * 16 + l15]);
    __syncthreads();

    // GEMM1: [48 x 64] @ [64 x 256]
    const unsigned short* pw1d = wsu + (size_t)OFF_PW1D * 2 + (size_t)l * 16384;
    f32x4 acc[3][4] = {};
    for (int ks = 0; ks < 2; ks++) {
        bf16x8 a[3];
        int kb = ks * 4 + g;
#pragma unroll
        for (int mt = 0; mt < 3; mt++) {
            int row = mt * 16 + l15;
            a[mt] = *(const bf16x8*)&s_u[(row << 6) + ((kb ^ (row & 7)) << 3)];
        }
#pragma unroll
        for (int nt = 0; nt < 4; nt++) {
            bf16x8 bf = *(const bf16x8*)&pw1d[((size_t)(ks * 16 + w * 4 + nt) * 64 + ln) * 8];
#pragma unroll
            for (int mt = 0; mt < 3; mt++)
                acc[mt][nt] = __builtin_amdgcn_mfma_f32_16x16x32_bf16(a[mt], bf, acc[mt][nt], 0, 0, 0);
        }
    }
    __syncthreads();   // all demb reads done; ef1 may now overwrite the aliased region
#pragma unroll
    for (int mt = 0; mt < 3; mt++)
#pragma unroll
        for (int nt = 0; nt < 4; nt++) {
            int col = w * 64 + nt * 16 + l15;
#pragma unroll
            for (int r = 0; r < 4; r++) {
                int row = mt * 16 + 4 * g + r;
                int hi = (row >= 24);
                int j = row - 24 * hi;
                float pj = bf2f(partjh[(size_t)(n0i + j) * 256 + col]);   // L2 hit (12 blocks/graph share)
                float v = acc[mt][nt][r] + pIv[hi][nt] + pj;
                s_u[(row << 8) + ((((col >> 3) ^ (row & 7))) << 3) + (col & 7)] = f2bf(silu_f(v));
            }
        }
    __syncthreads();
    // GEMM2: [48 x 256] @ [256 x 256]
    const unsigned short* pw2 = wsu + (size_t)OFF_PW2 * 2 + (size_t)l * 65536;
    f32x4 acc2[3][4] = {};
    for (int ks = 0; ks < 8; ks++) {
        bf16x8 a[3];
        int kb = ks * 4 + g;
#pragma unroll
        for (int mt = 0; mt < 3; mt++) {
            int row = mt * 16 + l15;
            a[mt] = *(const bf16x8*)&s_u[(row << 8) + ((kb ^ (row & 7)) << 3)];
        }
#pragma unroll
        for (int nt = 0; nt < 4; nt++) {
            bf16x8 bf = *(const bf16x8*)&pw2[((size_t)(ks * 16 + w * 4 + nt) * 64 + ln) * 8];
#pragma unroll
            for (int mt = 0; mt < 3; mt++)
                acc2[mt][nt] = __builtin_amdgcn_mfma_f32_16x16x32_bf16(a[mt], bf, acc2[mt][nt], 0, 0, 0);
        }
    }
    // in-register silu + aggregation over 24 edges per i-group
    float s0[4] = {}, s1[4] = {};
#pragma unroll
    for (int nt = 0; nt < 4; nt++) {
        int col = w * 64 + nt * 16 + l15;
        float b2 = eb2[l * 256 + col];
#pragma unroll
        for (int r = 0; r < 4; r++) s0[nt] += silu_f(acc2[0][nt][r] + b2);
        float m = 0.f;
#pragma unroll
        for (int r = 0; r < 4; r++) m += silu_f(acc2[1][nt][r] + b2);
        if (g < 2) s0[nt] += m; else s1[nt] += m;
#pragma unroll
        for (int r = 0; r < 4; r++) s1[nt] += silu_f(acc2[2][nt][r] + b2);
    }
#pragma unroll
    for (int nt = 0; nt < 4; nt++) {
        s0[nt] += __shfl_xor(s0[nt], 16);
        s0[nt] += __shfl_xor(s0[nt], 32);
        s1[nt] += __shfl_xor(s1[nt], 16);
        s1[nt] += __shfl_xor(s1[nt], 32);
    }
    unsigned short* aggh = (unsigned short*)ws + (size_t)OFF_AGGH * 2;
    if (g == 0) {
#pragma unroll
        for (int nt = 0; nt < 4; nt++) {
            int col = w * 64 + nt * 16 + l15;
            aggh[(size_t)(n0i + i0) * 256 + col]     = f2bf(s0[nt] * (1.0f / 24.0f));
            aggh[(size_t)(n0i + i0 + 1) * 256 + col] = f2bf(s1[nt] * (1.0f / 24.0f));
        }
    }
}

// ---------------- tail: node-MLP(3) + types + coords + nf-out + lattice, graph-aligned ----------------
// 128 blocks x 512 threads; 24 real rows padded to M=32 (pad rows' outputs discarded)
__global__ void __launch_bounds__(512) k_tail(const float* nb1, const float* nb2,
                                              const float* b_type, const float* w_coord,
                                              const float* lattices, const float* w_latt,
                                              float* ws, float* out) {
    __shared__ __align__(16) unsigned short s_in[32][536];
    __shared__ __align__(16) unsigned short s_h[32][264];
    __shared__ float gf[256];
    __shared__ float lo[9];
    float (*s_nf)[260] = (float(*)[260])&s_in[0][0];       // alias: valid after residual reads
    unsigned short (*s_a)[264] = s_h;                       // alias: valid after GEMM2 reads
    int tid = threadIdx.x, w = tid >> 6, ln = tid & 63;
    int l15 = ln & 15, g = ln >> 4;
    int b = blockIdx.x, n0 = b * 24;
    const unsigned short* wsu = (const unsigned short*)ws;
    const int lp = 3;
    const unsigned short* nfmidh = wsu + (size_t)OFF_NFMIDH * 2;
    const unsigned short* aggh   = wsu + (size_t)OFF_AGGH * 2;
    for (int idx = tid; idx < 1024; idx += 512) {
        int row = idx >> 5, c8 = idx & 31;
        int rr = (row < 24) ? row : 0;
        *(uint4*)&s_in[row][c8 * 8]       = *(const uint4*)&nfmidh[(size_t)(n0 + rr) * 256 + c8 * 8];
        *(uint4*)&s_in[row][256 + c8 * 8] = *(const uint4*)&aggh[(size_t)(n0 + rr) * 256 + c8 * 8];
    }
    __syncthreads();
    // GEMM1: [32 x 512] @ [512 x 256]; wave w -> nt16 = 2w,2w+1
    const unsigned short* p1 = wsu + (size_t)OFF_PNW1 * 2 + (size_t)lp * 131072;
    f32x4 acc[2][2] = {};
    for (int ks = 0; ks < 16; ks++) {
        bf16x8 a0 = *(const bf16x8*)&s_in[l15][ks * 32 + g * 8];
        bf16x8 a1 = *(const bf16x8*)&s_in[16 + l15][ks * 32 + g * 8];
#pragma unroll
        for (int q = 0; q < 2; q++) {
            bf16x8 bf = *(const bf16x8*)&p1[((size_t)(ks * 16 + 2 * w + q) * 64 + ln) * 8];
            acc[0][q] = __builtin_amdgcn_mfma_f32_16x16x32_bf16(a0, bf, acc[0][q], 0, 0, 0);
            acc[1][q] = __builtin_amdgcn_mfma_f32_16x16x32_bf16(a1, bf, acc[1][q], 0, 0, 0);
        }
    }
#pragma unroll
    for (int q = 0; q < 2; q++) {
        int col = w * 32 + q * 16 + l15;
        float b1 = nb1[lp * 256 + col];
#pragma unroll
        for (int mt = 0; mt < 2; mt++)
#pragma unroll
            for (int r = 0; r < 4; r++) s_h[mt * 16 + 4 * g + r][col] = f2bf(silu_f(acc[mt][q][r] + b1));
    }
    __syncthreads();
    // GEMM2: [32 x 256] @ [256 x 256]
    const unsigned short* p2 = wsu + (size_t)OFF_PNW2 * 2 + (size_t)lp * 65536;
    f32x4 a2[2][2] = {};
    for (int ks = 0; ks < 8; ks++) {
        bf16x8 a0 = *(const bf16x8*)&s_h[l15][ks * 32 + g * 8];
        bf16x8 a1 = *(const bf16x8*)&s_h[16 + l15][ks * 32 + g * 8];
#pragma unroll
        for (int q = 0; q < 2; q++) {
            bf16x8 bf = *(const bf16x8*)&p2[((size_t)(ks * 16 + 2 * w + q) * 64 + ln) * 8];
            a2[0][q] = __builtin_amdgcn_mfma_f32_16x16x32_bf16(a0, bf, a2[0][q], 0, 0, 0);
            a2[1][q] = __builtin_amdgcn_mfma_f32_16x16x32_bf16(a1, bf, a2[1][q], 0, 0, 0);
        }
    }
    // read residuals before aliasing s_in
    float res[2][2][4];
#pragma unroll
    for (int q = 0; q < 2; q++) {
        int col = w * 32 + q * 16 + l15;
#pragma unroll
        for (int mt = 0; mt < 2; mt++)
#pragma unroll
            for (int r = 0; r < 4; r++) res[mt][q][r] = bf2f(s_in[mt * 16 + 4 * g + r][col]);
    }
    __syncthreads();   // all s_in / s_h reads done; aliases become writable
#pragma unroll
    for (int q = 0; q < 2; q++) {
        int col = w * 32 + q * 16 + l15;
        float b2 = nb2[lp * 256 + col];
#pragma unroll
        for (int mt = 0; mt < 2; mt++)
#pragma unroll
            for (int r = 0; r < 4; r++) {
                int row = mt * 16 + 4 * g + r;
                float v = res[mt][q][r] + silu_f(a2[mt][q][r] + b2);
                if (row < 24) {
                    s_nf[row][col] = v;
                    out[OUT_NF + (size_t)(n0 + row) * 256 + col] = v;
                }
                s_a[row][col] = f2bf(v);
            }
    }
    __syncthreads();
    // types GEMM: [32 x 256] @ [256 x 112] — waves 0..6
    if (w < 7) {
        const unsigned short* pt = wsu + (size_t)OFF_PWTYPE * 2;
        f32x4 at2[2] = {};
        for (int ks = 0; ks < 8; ks++) {
            bf16x8 a0 = *(const bf16x8*)&s_a[l15][ks * 32 + g * 8];
            bf16x8 a1 = *(const bf16x8*)&s_a[16 + l15][ks * 32 + g * 8];
            bf16x8 bf = *(const bf16x8*)&pt[((size_t)(ks * 7 + w) * 64 + ln) * 8];
            at2[0] = __builtin_amdgcn_mfma_f32_16x16x32_bf16(a0, bf, at2[0], 0, 0, 0);
            at2[1] = __builtin_amdgcn_mfma_f32_16x16x32_bf16(a1, bf, at2[1], 0, 0, 0);
        }
        int a_col = w * 16 + l15;
        if (a_col < 103) {
            float bt = b_type[a_col];
#pragma unroll
            for (int mt = 0; mt < 2; mt++)
#pragma unroll
                for (int r = 0; r < 4; r++) {
                    int row = mt * 16 + 4 * g + r;
                    if (row < 24)
                        out[OUT_TYPES + (size_t)(n0 + row) * 103 + a_col] = at2[mt][r] + bt;
                }
        }
    }
    // coords: 24x3 dots over K=256
    if (tid < 72) {
        int p = tid / 3, cc = tid % 3;
        float a0 = 0.f;
        for (int k = 0; k < 256; k++) a0 += s_nf[p][k] * w_coord[cc * 256 + k];
        out[OUT_COORD + (size_t)(n0 + p) * 3 + cc] = a0;
    }
    // gfeat mean
    if (tid < 256) {
        float s = 0.f;
#pragma unroll
        for (int i = 0; i < 24; i++) s += s_nf[i][tid];
        gf[tid] = s * (1.0f / 24.0f);
    }
    __syncthreads();
    if (tid < 9) {
        float a0 = 0.f;
        for (int k = 0; k < 256; k++) a0 += gf[k] * w_latt[tid * 256 + k];
        lo[tid] = a0;
    }
    __syncthreads();
    if (tid < 9) {
        int i = tid / 3, kk = tid % 3;
        float a0 = 0.f;
#pragma unroll
        for (int j = 0; j < 3; j++) a0 += lo[i * 3 + j] * lattices[b * 9 + j * 3 + kk];
        out[OUT_LATT + (size_t)b * 9 + tid] = a0;
    }
}

extern "C" void kernel_launch(void* const* d_in, const int* in_sizes, int n_in,
                              void* d_out, int out_size, void* d_ws, size_t ws_size,
                              hipStream_t stream) {
    const float* atom_types = (const float*)d_in[0];
    const float* frac       = (const float*)d_in[1];
    const float* lattices   = (const float*)d_in[2];
    const float* t_in       = (const float*)d_in[3];
    const float* text       = (const float*)d_in[4];
    const float* w_emb      = (const float*)d_in[5];
    const float* b_emb      = (const float*)d_in[6];
    const float* w_cond     = (const float*)d_in[7];
    const float* b_cond     = (const float*)d_in[8];
    const float* w_proj     = (const float*)d_in[9];
    const float* b_proj     = (const float*)d_in[10];
    const float* film_g     = (const float*)d_in[11];
    const float* film_b     = (const float*)d_in[12];
    const float* ew1        = (const float*)d_in[13];
    const float* eb1        = (const float*)d_in[14];
    const float* ew2        = (const float*)d_in[15];
    const float* eb2        = (const float*)d_in[16];
    const float* nw1        = (const float*)d_in[17];
    const float* nb1        = (const float*)d_in[18];
    const float* nw2        = (const float*)d_in[19];
    const float* nb2        = (const float*)d_in[20];
    const float* w_coord    = (const float*)d_in[21];
    const float* w_latt     = (const float*)d_in[22];
    const float* w_type     = (const float*)d_in[23];
    const float* b_type     = (const float*)d_in[24];
    float* ws  = (float*)d_ws;
    float* out = (float*)d_out;

    k_prep<<<7700, 256, 0, stream>>>(w_emb, w_cond, w_proj, ew1, ew2, nw1, nw2, w_type, ws);
    k_setup<<<8, 256, 0, stream>>>(lattices, t_in, text, b_cond, ws);
    for (int l = 0; l < NLAYERS; l++) {
        k_fnf<<<N_ / 16, 512, 0, stream>>>(l, atom_types, b_emb, nb1, nb2,
                                           b_proj, film_g, film_b, eb1, ws);
        k_edge<<<N_ * 12 / 24, 256, 0, stream>>>(l, frac, eb2, ws);
    }
    k_tail<<<B_, 512, 0, stream>>>(nb1, nb2, b_type, w_coord, lattices, w_latt, ws, out);
}

// Round 11
// 381.060 us; speedup vs baseline: 1.0968x; 1.0968x over previous
//
#include <hip/hip_runtime.h>
#include <math.h>

// ---- problem constants ----
#define B_      128
#define A_      24
#define N_      3072     // B_*A_
#define NLAYERS 4

// ---- workspace layout (float-element offsets) ----
// NOTE: each [3072][256] bf16 buffer = 786432 ushorts = 393216 float slots.
#define OFF_COND    0         // [128][512] f32                      (65536)
#define OFF_LATW    65536     // [4][128][256] f32                   (131072)
#define OFF_NFMIDH  196608    // [3072][256] bf16                    (393216)
#define OFF_AGGH    589824    // [3072][256] bf16                    (393216)
#define OFF_PARTIH  983040    // [3072][256] bf16 (incl. eb1+latW)   (393216)
#define OFF_PARTJH  1376256   // [3072][256] bf16                    (393216)
#define OFF_W1LATT  1769472   // [4][9][256] f32                     (9216)
#define OFF_PW1A    1778688   // [4][8][16][64][8] bf16              (131072)
#define OFF_PW1B    1909760   //                                     (131072)
#define OFF_PW1D    2040832   // [4][2][16][64][8] bf16              (32768)
#define OFF_PW2     2073600   // [4][8][16][64][8] bf16              (131072)
#define OFF_PWPROJ  2204672   // [8][16][64][8] bf16                 (32768)
#define OFF_PNW1    2237440   // [4][16][16][64][8] bf16             (262144)
#define OFF_PNW2    2499584   // [4][8][16][64][8] bf16              (131072)
#define OFF_PWEMB   2630656   // [4 ks][16 nt][64][8] bf16 (K pad)   (16384)
#define OFF_PWCOND  2647040   // [12 ks][32 nt][64][8] bf16 (K=384)  (98304)
#define OFF_PWTYPE  2745344   // [8 ks][7 nt][64][8] bf16 (N pad)    (14336)
// end 2759680 floats ~ 10.5 MiB

// output offsets (floats): types | lattice | coords | nf
#define OUT_TYPES  0
#define OUT_LATT   316416
#define OUT_COORD  317568
#define OUT_NF     326784

typedef __attribute__((ext_vector_type(8))) short bf16x8;
typedef __attribute__((ext_vector_type(4))) float f32x4;

__device__ __forceinline__ float silu_f(float x) { return x / (1.0f + __expf(-x)); }
__device__ __forceinline__ unsigned short f2bf(float x) {
    unsigned int u = __float_as_uint(x);
    return (unsigned short)((u + 0x7FFFu + ((u >> 16) & 1u)) >> 16);
}
__device__ __forceinline__ float bf2f(unsigned short h) {
    return __uint_as_float(((unsigned int)h) << 16);
}

// ---------------- weight packs ----------------
// generic pack: pack[((ks*NT + nt)*64 + lane)*8 + j] = W[k][n],
//   k = ks*32 + (lane>>4)*8 + j,  n = nt*16 + (lane&15)
__global__ void k_prep(const float* w_emb, const float* w_cond, const float* w_proj,
                       const float* ew1, const float* ew2, const float* nw1, const float* nw2,
                       const float* w_type, float* ws) {
    int idx = blockIdx.x * blockDim.x + threadIdx.x;
    unsigned short* pu = (unsigned short*)ws;
    int i = idx;
    if (i < 9216)   { int l = i / 2304, r = (i % 2304) / 256, h = i % 256;
                      ws[OFF_W1LATT + i] = ew1[((size_t)l * 256 + h) * 581 + 512 + r]; return; }        i -= 9216;
    if (i < 262144) { int l = i >> 16, r = i & 65535, ks = r >> 13, r2 = r & 8191,
                      nt = r2 >> 9, r3 = r2 & 511, lane = r3 >> 3, j = r3 & 7;
                      int k = ks * 32 + (lane >> 4) * 8 + j, n = nt * 16 + (lane & 15);
                      pu[(size_t)OFF_PW1A * 2 + i] = f2bf(ew1[((size_t)l * 256 + n) * 581 + k]); return; } i -= 262144;
    if (i < 262144) { int l = i >> 16, r = i & 65535, ks = r >> 13, r2 = r & 8191,
                      nt = r2 >> 9, r3 = r2 & 511, lane = r3 >> 3, j = r3 & 7;
                      int k = ks * 32 + (lane >> 4) * 8 + j, n = nt * 16 + (lane & 15);
                      pu[(size_t)OFF_PW1B * 2 + i] = f2bf(ew1[((size_t)l * 256 + n) * 581 + 256 + k]); return; } i -= 262144;
    if (i < 65536)  { int l = i >> 14, r = i & 16383, ks = r >> 13, r2 = r & 8191,
                      nt = r2 >> 9, r3 = r2 & 511, lane = r3 >> 3, j = r3 & 7;
                      int kp = ks * 32 + (lane >> 4) * 8 + j, n = nt * 16 + (lane & 15);
                      float v = (kp < 60) ? ew1[((size_t)l * 256 + n) * 581 + 521 + kp] : 0.0f;
                      pu[(size_t)OFF_PW1D * 2 + i] = f2bf(v); return; }                                  i -= 65536;
    if (i < 262144) { int l = i >> 16, r = i & 65535, ks = r >> 13, r2 = r & 8191,
                      nt = r2 >> 9, r3 = r2 & 511, lane = r3 >> 3, j = r3 & 7;
                      int k = ks * 32 + (lane >> 4) * 8 + j, n = nt * 16 + (lane & 15);
                      pu[(size_t)OFF_PW2 * 2 + i] = f2bf(ew2[((size_t)l * 256 + n) * 256 + k]); return; } i -= 262144;
    if (i < 65536)  { int ks = i >> 13, r2 = i & 8191,
                      nt = r2 >> 9, r3 = r2 & 511, lane = r3 >> 3, j = r3 & 7;
                      int k = ks * 32 + (lane >> 4) * 8 + j, n = nt * 16 + (lane & 15);
                      pu[(size_t)OFF_PWPROJ * 2 + i] = f2bf(w_proj[(size_t)n * 256 + k]); return; }      i -= 65536;
    if (i < 524288) { int l = i >> 17, r = i & 131071, ks = r >> 13, r2 = r & 8191,
                      nt = r2 >> 9, r3 = r2 & 511, lane = r3 >> 3, j = r3 & 7;
                      int k = ks * 32 + (lane >> 4) * 8 + j, n = nt * 16 + (lane & 15);
                      pu[(size_t)OFF_PNW1 * 2 + i] = f2bf(nw1[((size_t)l * 256 + n) * 512 + k]); return; } i -= 524288;
    if (i < 262144) { int l = i >> 16, r = i & 65535, ks = r >> 13, r2 = r & 8191,
                      nt = r2 >> 9, r3 = r2 & 511, lane = r3 >> 3, j = r3 & 7;
                      int k = ks * 32 + (lane >> 4) * 8 + j, n = nt * 16 + (lane & 15);
                      pu[(size_t)OFF_PNW2 * 2 + i] = f2bf(nw2[((size_t)l * 256 + n) * 256 + k]); return; } i -= 262144;
    if (i < 32768)  { int ks = i >> 13, r2 = i & 8191,
                      nt = r2 >> 9, r3 = r2 & 511, lane = r3 >> 3, j = r3 & 7;
                      int k = ks * 32 + (lane >> 4) * 8 + j, n = nt * 16 + (lane & 15);
                      float v = (k < 103) ? w_emb[(size_t)n * 103 + k] : 0.0f;
                      pu[(size_t)OFF_PWEMB * 2 + i] = f2bf(v); return; }                                 i -= 32768;
    if (i < 196608) { int ks = i / 16384, r2 = i & 16383,
                      nt = r2 >> 9, r3 = r2 & 511, lane = r3 >> 3, j = r3 & 7;
                      int k = ks * 32 + (lane >> 4) * 8 + j, n = nt * 16 + (lane & 15);
                      pu[(size_t)OFF_PWCOND * 2 + i] = f2bf(w_cond[(size_t)n * 384 + k]); return; }      i -= 196608;
    { int ks = i / 3584, r2 = i % 3584,
      nt = r2 >> 9, r3 = r2 & 511, lane = r3 >> 3, j = r3 & 7;
      int k = ks * 32 + (lane >> 4) * 8 + j, a = nt * 16 + (lane & 15);
      float v = (a < 103) ? w_type[(size_t)a * 256 + k] : 0.0f;
      pu[(size_t)OFF_PWTYPE * 2 + i] = f2bf(v); }
}

// ---------------- setup: latips + latW + cond (MFMA), 8 blocks x 16 graphs ----------------
__global__ void __launch_bounds__(256) k_setup(const float* lat, const float* t_in, const float* tx,
                                               const float* b_cond, float* ws) {
    __shared__ __align__(16) unsigned short s_ct[16][392];
    __shared__ float s_lat[16][9];
    int tid = threadIdx.x, w = tid >> 6, ln = tid & 63;
    int l15 = ln & 15, g = ln >> 4;
    int g0 = blockIdx.x * 16;
    if (tid < 144) {
        int gl = tid / 9, r = tid % 9, ii = r / 3, kk = r % 3;
        const float* L = lat + (g0 + gl) * 9;
        s_lat[gl][r] = L[ii*3+0]*L[kk*3+0] + L[ii*3+1]*L[kk*3+1] + L[ii*3+2]*L[kk*3+2];
    }
    for (int idx = tid; idx < 16 * 384; idx += 256) {
        int row = idx / 384, k = idx % 384;
        float v = (k < 256) ? t_in[(size_t)(g0 + row) * 256 + k] : tx[(size_t)(g0 + row) * 128 + (k - 256)];
        s_ct[row][k] = f2bf(v);
    }
    __syncthreads();
    for (int idx = tid; idx < 16384; idx += 256) {
        int l = idx >> 12, gl = (idx >> 8) & 15, h = idx & 255;
        float a = 0.f;
#pragma unroll
        for (int r = 0; r < 9; r++) a += s_lat[gl][r] * ws[OFF_W1LATT + (l * 9 + r) * 256 + h];
        ws[OFF_LATW + (size_t)(l * 128 + g0 + gl) * 256 + h] = a;
    }
    const unsigned short* pc = (const unsigned short*)ws + (size_t)OFF_PWCOND * 2;
    f32x4 acc[8] = {};
    for (int ks = 0; ks < 12; ks++) {
        bf16x8 a = *(const bf16x8*)&s_ct[l15][ks * 32 + g * 8];
#pragma unroll
        for (int q = 0; q < 8; q++) {
            int nt = w * 8 + q;
            bf16x8 bf = *(const bf16x8*)&pc[((size_t)(ks * 32 + nt) * 64 + ln) * 8];
            acc[q] = __builtin_amdgcn_mfma_f32_16x16x32_bf16(a, bf, acc[q], 0, 0, 0);
        }
    }
#pragma unroll
    for (int q = 0; q < 8; q++) {
        int col = w * 128 + q * 16 + l15;
        float bc = b_cond[col];
#pragma unroll
        for (int r = 0; r < 4; r++) {
            int gg = g0 + 4 * g + r;
            ws[OFF_COND + (size_t)gg * 512 + col] = silu_f(acc[q][r] + bc);
        }
    }
}

// ---------------- fused node-MLP(l-1) [or embed] + FiLM(l) + PartI/PartJ(l) ----------------
// 512 threads / 8 waves; wave w owns N-tiles nt16 = 2w, 2w+1 (cols 32w..32w+31)
__global__ void __launch_bounds__(512) k_fnf(int l, const float* at, const float* b_emb,
                                             const float* nb1, const float* nb2,
                                             const float* b_proj, const float* film_g, const float* film_b,
                                             const float* eb1, float* ws) {
    __shared__ __align__(16) unsigned short s_in[16][536];
    __shared__ __align__(16) unsigned short s_h[16][264];
    __shared__ __align__(16) unsigned short s_a[16][264];
    __shared__ float s_nf[16][260];
    __shared__ float s_mu[16], s_rs[16];
    float (*s_c)[268] = (float(*)[268])&s_in[0][0];   // aliased over s_in (used after node phase)
    int tid = threadIdx.x, w = tid >> 6, ln = tid & 63;
    int l15 = ln & 15, g = ln >> 4;
    int n0 = blockIdx.x * 16;
    const unsigned short* wsu = (const unsigned short*)ws;
    unsigned short* wsw = (unsigned short*)ws;

    f32x4 accn[2] = {};
    if (l == 0) {
        // ---- embed: nf = at @ w_emb^T + b_emb ----
        for (int idx = tid; idx < 16 * 128; idx += 512) {
            int row = idx >> 7, k = idx & 127;
            s_in[row][k] = (k < 103) ? f2bf(at[(size_t)(n0 + row) * 103 + k]) : (unsigned short)0;
        }
        __syncthreads();
        const unsigned short* pe = wsu + (size_t)OFF_PWEMB * 2;
        for (int ks = 0; ks < 4; ks++) {
            bf16x8 a = *(const bf16x8*)&s_in[l15][ks * 32 + g * 8];
#pragma unroll
            for (int q = 0; q < 2; q++) {
                bf16x8 bf = *(const bf16x8*)&pe[((size_t)(ks * 16 + 2 * w + q) * 64 + ln) * 8];
                accn[q] = __builtin_amdgcn_mfma_f32_16x16x32_bf16(a, bf, accn[q], 0, 0, 0);
            }
        }
        __syncthreads();
#pragma unroll
        for (int q = 0; q < 2; q++) {
            int col = w * 32 + q * 16 + l15;
            float be = b_emb[col];
#pragma unroll
            for (int r = 0; r < 4; r++) {
                int row = 4 * g + r;
                float v = accn[q][r] + be;
                s_nf[row][col] = v;
                s_a[row][col] = f2bf(v);
            }
        }
    } else {
        // ---- node MLP of layer l-1 ----
        int lp = l - 1;
        const unsigned short* nfmidh = wsu + (size_t)OFF_NFMIDH * 2;
        const unsigned short* aggh   = wsu + (size_t)OFF_AGGH * 2;
        {
            int row = tid >> 5, c8 = tid & 31;
            *(uint4*)&s_in[row][c8 * 8]       = *(const uint4*)&nfmidh[(size_t)(n0 + row) * 256 + c8 * 8];
            *(uint4*)&s_in[row][256 + c8 * 8] = *(const uint4*)&aggh[(size_t)(n0 + row) * 256 + c8 * 8];
        }
        __syncthreads();
        const unsigned short* p1 = wsu + (size_t)OFF_PNW1 * 2 + (size_t)lp * 131072;
        f32x4 acc[2] = {};
        for (int ks = 0; ks < 16; ks++) {
            bf16x8 a = *(const bf16x8*)&s_in[l15][ks * 32 + g * 8];
#pragma unroll
            for (int q = 0; q < 2; q++) {
                bf16x8 bf = *(const bf16x8*)&p1[((size_t)(ks * 16 + 2 * w + q) * 64 + ln) * 8];
                acc[q] = __builtin_amdgcn_mfma_f32_16x16x32_bf16(a, bf, acc[q], 0, 0, 0);
            }
        }
#pragma unroll
        for (int q = 0; q < 2; q++) {
            int col = w * 32 + q * 16 + l15;
            float b1 = nb1[lp * 256 + col];
#pragma unroll
            for (int r = 0; r < 4; r++) s_h[4 * g + r][col] = f2bf(silu_f(acc[q][r] + b1));
        }
        __syncthreads();
        const unsigned short* p2 = wsu + (size_t)OFF_PNW2 * 2 + (size_t)lp * 65536;
        for (int ks = 0; ks < 8; ks++) {
            bf16x8 a = *(const bf16x8*)&s_h[l15][ks * 32 + g * 8];
#pragma unroll
            for (int q = 0; q < 2; q++) {
                bf16x8 bf = *(const bf16x8*)&p2[((size_t)(ks * 16 + 2 * w + q) * 64 + ln) * 8];
                accn[q] = __builtin_amdgcn_mfma_f32_16x16x32_bf16(a, bf, accn[q], 0, 0, 0);
            }
        }
#pragma unroll
        for (int q = 0; q < 2; q++) {
            int col = w * 32 + q * 16 + l15;
            float b2 = nb2[lp * 256 + col];
#pragma unroll
            for (int r = 0; r < 4; r++) {
                int row = 4 * g + r;
                float v = bf2f(s_in[row][col]) + silu_f(accn[q][r] + b2);
                s_nf[row][col] = v;
                s_a[row][col] = f2bf(v);
            }
        }
    }
    __syncthreads();
    // ---- proj GEMM: [16 x 256] @ [256 x 256] ----
    const unsigned short* pwp = wsu + (size_t)OFF_PWPROJ * 2;
    f32x4 accp[2] = {};
    for (int ks = 0; ks < 8; ks++) {
        bf16x8 a = *(const bf16x8*)&s_a[l15][ks * 32 + g * 8];
#pragma unroll
        for (int q = 0; q < 2; q++) {
            bf16x8 bf = *(const bf16x8*)&pwp[((size_t)(ks * 16 + 2 * w + q) * 64 + ln) * 8];
            accp[q] = __builtin_amdgcn_mfma_f32_16x16x32_bf16(a, bf, accp[q], 0, 0, 0);
        }
    }
    __syncthreads();  // s_in (node phase) fully read; s_c (alias) may be written
#pragma unroll
    for (int q = 0; q < 2; q++) {
        int col = w * 32 + q * 16 + l15;
        float bp = b_proj[col];
#pragma unroll
        for (int r = 0; r < 4; r++) s_c[4 * g + r][col] = accp[q][r] + bp;
    }
    __syncthreads();
    // ---- LN stats: wave w handles rows 2w, 2w+1 ----
    for (int r2 = 0; r2 < 2; r2++) {
        int row = w * 2 + r2;
        float s = 0.f, q = 0.f;
        for (int c = ln; c < 256; c += 64) { float v = s_c[row][c]; s += v; q += v * v; }
#pragma unroll
        for (int o = 1; o < 64; o <<= 1) { s += __shfl_xor(s, o); q += __shfl_xor(q, o); }
        if (ln == 0) {
            float mu = s * (1.0f / 256.0f);
            float var = q * (1.0f / 256.0f) - mu * mu;
            s_mu[row] = mu; s_rs[row] = rsqrtf(var + 1e-5f);
        }
    }
    __syncthreads();
    // ---- FiLM epilogue: col = tid&255, rows (tid>>8) + 2t ----
    {
        int col = tid & 255, rb = tid >> 8;
        float gg = film_g[col], bb = film_b[col];
        unsigned short* nfmidh = wsw + (size_t)OFF_NFMIDH * 2;
#pragma unroll
        for (int t = 0; t < 8; t++) {
            int row = rb + 2 * t;
            int n = n0 + row, b = n / 24;
            float sc = ws[OFF_COND + (size_t)b * 512 + col];
            float sh = ws[OFF_COND + (size_t)b * 512 + 256 + col];
            float yn = (s_c[row][col] - s_mu[row]) * s_rs[row] * gg + bb;
            float outv = s_nf[row][col] + silu_f(yn * sc + sh);
            unsigned short ob = f2bf(outv);
            nfmidh[(size_t)n * 256 + col] = ob;
            s_a[row][col] = ob;
        }
    }
    __syncthreads();
    // ---- PartI/PartJ GEMMs ----
    const unsigned short* pA = wsu + (size_t)OFF_PW1A * 2 + (size_t)l * 65536;
    const unsigned short* pB = wsu + (size_t)OFF_PW1B * 2 + (size_t)l * 65536;
    f32x4 aI[2] = {}, aJ[2] = {};
    for (int ks = 0; ks < 8; ks++) {
        bf16x8 a = *(const bf16x8*)&s_a[l15][ks * 32 + g * 8];
#pragma unroll
        for (int q = 0; q < 2; q++) {
            bf16x8 bi = *(const bf16x8*)&pA[((size_t)(ks * 16 + 2 * w + q) * 64 + ln) * 8];
            bf16x8 bj = *(const bf16x8*)&pB[((size_t)(ks * 16 + 2 * w + q) * 64 + ln) * 8];
            aI[q] = __builtin_amdgcn_mfma_f32_16x16x32_bf16(a, bi, aI[q], 0, 0, 0);
            aJ[q] = __builtin_amdgcn_mfma_f32_16x16x32_bf16(a, bj, aJ[q], 0, 0, 0);
        }
    }
    unsigned short* partih = wsw + (size_t)OFF_PARTIH * 2;
    unsigned short* partjh = wsw + (size_t)OFF_PARTJH * 2;
#pragma unroll
    for (int q = 0; q < 2; q++) {
        int col = w * 32 + q * 16 + l15;
        float e1 = eb1[l * 256 + col];
#pragma unroll
        for (int r = 0; r < 4; r++) {
            int n = n0 + 4 * g + r;
            int gb = n / 24;
            float vi = aI[q][r] + e1 + ws[OFF_LATW + (size_t)(l * 128 + gb) * 256 + col];
            partih[(size_t)n * 256 + col] = f2bf(vi);
            partjh[(size_t)n * 256 + col] = f2bf(aJ[q][r]);
        }
    }
}

// ---------------- fused edge pipeline (C-seed adds; pJ/demb packed in ef1 buffer; 6 blocks/CU) ----------------
// s_u phases: [0,6336) pJ stage | [6336,12480) demb | after both consumed: [0,12288) ef1
#define SU_WORDS 12480
#define DOFF     6336
__global__ void __launch_bounds__(256, 6) k_edge(int l, const float* frac, const float* eb2, float* ws) {
    __shared__ __align__(16) unsigned short s_u[SU_WORDS];
    __shared__ __align__(16) unsigned short s_pI[2][264];
    __shared__ float s_fc[24][3];
    int tid = threadIdx.x, w = tid >> 6, ln = tid & 63;
    int l15 = ln & 15, g = ln >> 4;
    int b = blockIdx.x & 127, c = blockIdx.x >> 7;
    int i0 = c * 2, n0i = b * 24;
    const unsigned short* wsu = (const unsigned short*)ws;

    // ---- phase 1: stage fc, pJ (coalesced into s_u[0..6336)), pI ----
    const unsigned short* partjh = wsu + (size_t)OFF_PARTJH * 2 + (size_t)n0i * 256;
    const unsigned short* partih = wsu + (size_t)OFF_PARTIH * 2 + (size_t)(n0i + i0) * 256;
    for (int idx = tid; idx < 72; idx += 256) s_fc[idx / 3][idx % 3] = frac[b * 72 + idx];
    for (int idx = tid; idx < 768; idx += 256) {
        int row = idx >> 5, c8 = idx & 31;
        *(uint4*)&s_u[row * 264 + c8 * 8] = *(const uint4*)&partjh[row * 256 + c8 * 8];
    }
    if (tid < 64) {
        int row = tid >> 5, c8 = tid & 31;
        *(uint4*)&s_pI[row][c8 * 8] = *(const uint4*)&partih[row * 256 + c8 * 8];
    }
    __syncthreads();
    // ---- phase 2: seed acc = pI + pJ (C-in for GEMM1); write demb to [DOFF..) ----
    float pIv[2][4];
#pragma unroll
    for (int hi = 0; hi < 2; hi++)
#pragma unroll
        for (int nt = 0; nt < 4; nt++) pIv[hi][nt] = bf2f(s_pI[hi][w * 64 + nt * 16 + l15]);
    f32x4 acc[3][4];
#pragma unroll
    for (int mt = 0; mt < 3; mt++)
#pragma unroll
        for (int nt = 0; nt < 4; nt++) {
            int col = w * 64 + nt * 16 + l15;
#pragma unroll
            for (int r = 0; r < 4; r++) {
                int row = mt * 16 + 4 * g + r;
                int hi = (row >= 24);
                int j = row - 24 * hi;
                acc[mt][nt][r] = pIv[hi][nt] + bf2f(s_u[j * 264 + col]);
            }
        }
    for (int idx = tid; idx < 3072; idx += 256) {
        int row = idx >> 6, k = idx & 63;
        unsigned short v = 0;
        if (k < 60) {
            int kk = (k < 30) ? k : k - 30;
            int d = kk / 10, f = kk % 10;
            int hi = (row >= 24);
            int j = row - (hi ? 24 : 0);
            float fd = s_fc[j][d] - s_fc[i0 + hi][d];
            fd -= floorf(fd);
            float ang = fd * (6.283185307179586f * (float)f);
            v = f2bf((k < 30) ? __sinf(ang) : __cosf(ang));
        }
        s_u[DOFF + (row << 6) + (((k >> 3) ^ (row & 7)) << 3) + (k & 7)] = v;
    }
    __syncthreads();
    // ---- GEMM1: [48 x 64] @ [64 x 256], accumulating on seeded C ----
    const unsigned short* pw1d = wsu + (size_t)OFF_PW1D * 2 + (size_t)l * 16384;
    for (int ks = 0; ks < 2; ks++) {
        bf16x8 a[3];
        int kb = ks * 4 + g;
#pragma unroll
        for (int mt = 0; mt < 3; mt++) {
            int row = mt * 16 + l15;
            a[mt] = *(const bf16x8*)&s_u[DOFF + (row << 6) + ((kb ^ (row & 7)) << 3)];
        }
#pragma unroll
        for (int nt = 0; nt < 4; nt++) {
            bf16x8 bf = *(const bf16x8*)&pw1d[((size_t)(ks * 16 + w * 4 + nt) * 64 + ln) * 8];
#pragma unroll
            for (int mt = 0; mt < 3; mt++)
                acc[mt][nt] = __builtin_amdgcn_mfma_f32_16x16x32_bf16(a[mt], bf, acc[mt][nt], 0, 0, 0);
        }
    }
    __syncthreads();   // all pJ/demb reads done; ef1 may overwrite s_u
    // ---- epilogue: ef1 = silu(acc), swizzled ----
#pragma unroll
    for (int mt = 0; mt < 3; mt++)
#pragma unroll
        for (int nt = 0; nt < 4; nt++) {
            int col = w * 64 + nt * 16 + l15;
#pragma unroll
            for (int r = 0; r < 4; r++) {
                int row = mt * 16 + 4 * g + r;
                s_u[(row << 8) + ((((col >> 3) ^ (row & 7))) << 3) + (col & 7)] = f2bf(silu_f(acc[mt][nt][r]));
            }
        }
    __syncthreads();
    // ---- GEMM2: [48 x 256] @ [256 x 256] ----
    const unsigned short* pw2 = wsu + (size_t)OFF_PW2 * 2 + (size_t)l * 65536;
    f32x4 acc2[3][4] = {};
    for (int ks = 0; ks < 8; ks++) {
        bf16x8 a[3];
        int kb = ks * 4 + g;
#pragma unroll
        for (int mt = 0; mt < 3; mt++) {
            int row = mt * 16 + l15;
            a[mt] = *(const bf16x8*)&s_u[(row << 8) + ((kb ^ (row & 7)) << 3)];
        }
#pragma unroll
        for (int nt = 0; nt < 4; nt++) {
            bf16x8 bf = *(const bf16x8*)&pw2[((size_t)(ks * 16 + w * 4 + nt) * 64 + ln) * 8];
#pragma unroll
            for (int mt = 0; mt < 3; mt++)
                acc2[mt][nt] = __builtin_amdgcn_mfma_f32_16x16x32_bf16(a[mt], bf, acc2[mt][nt], 0, 0, 0);
        }
    }
    // ---- in-register silu + aggregation over 24 edges per i-group ----
    float s0[4] = {}, s1[4] = {};
#pragma unroll
    for (int nt = 0; nt < 4; nt++) {
        int col = w * 64 + nt * 16 + l15;
        float b2 = eb2[l * 256 + col];
#pragma unroll
        for (int r = 0; r < 4; r++) s0[nt] += silu_f(acc2[0][nt][r] + b2);
        float m = 0.f;
#pragma unroll
        for (int r = 0; r < 4; r++) m += silu_f(acc2[1][nt][r] + b2);
        if (g < 2) s0[nt] += m; else s1[nt] += m;
#pragma unroll
        for (int r = 0; r < 4; r++) s1[nt] += silu_f(acc2[2][nt][r] + b2);
    }
#pragma unroll
    for (int nt = 0; nt < 4; nt++) {
        s0[nt] += __shfl_xor(s0[nt], 16);
        s0[nt] += __shfl_xor(s0[nt], 32);
        s1[nt] += __shfl_xor(s1[nt], 16);
        s1[nt] += __shfl_xor(s1[nt], 32);
    }
    unsigned short* aggh = (unsigned short*)ws + (size_t)OFF_AGGH * 2;
    if (g == 0) {
#pragma unroll
        for (int nt = 0; nt < 4; nt++) {
            int col = w * 64 + nt * 16 + l15;
            aggh[(size_t)(n0i + i0) * 256 + col]     = f2bf(s0[nt] * (1.0f / 24.0f));
            aggh[(size_t)(n0i + i0 + 1) * 256 + col] = f2bf(s1[nt] * (1.0f / 24.0f));
        }
    }
}

// ---------------- tail: node-MLP(3) + types + coords + nf-out + lattice, graph-aligned ----------------
// 128 blocks x 512 threads; 24 real rows padded to M=32 (pad rows' outputs discarded)
__global__ void __launch_bounds__(512) k_tail(const float* nb1, const float* nb2,
                                              const float* b_type, const float* w_coord,
                                              const float* lattices, const float* w_latt,
                                              float* ws, float* out) {
    __shared__ __align__(16) unsigned short s_in[32][536];
    __shared__ __align__(16) unsigned short s_h[32][264];
    __shared__ float gf[256];
    __shared__ float lo[9];
    float (*s_nf)[260] = (float(*)[260])&s_in[0][0];       // alias: valid after residual reads
    unsigned short (*s_a)[264] = s_h;                       // alias: valid after GEMM2 reads
    int tid = threadIdx.x, w = tid >> 6, ln = tid & 63;
    int l15 = ln & 15, g = ln >> 4;
    int b = blockIdx.x, n0 = b * 24;
    const unsigned short* wsu = (const unsigned short*)ws;
    const int lp = 3;
    const unsigned short* nfmidh = wsu + (size_t)OFF_NFMIDH * 2;
    const unsigned short* aggh   = wsu + (size_t)OFF_AGGH * 2;
    for (int idx = tid; idx < 1024; idx += 512) {
        int row = idx >> 5, c8 = idx & 31;
        int rr = (row < 24) ? row : 0;
        *(uint4*)&s_in[row][c8 * 8]       = *(const uint4*)&nfmidh[(size_t)(n0 + rr) * 256 + c8 * 8];
        *(uint4*)&s_in[row][256 + c8 * 8] = *(const uint4*)&aggh[(size_t)(n0 + rr) * 256 + c8 * 8];
    }
    __syncthreads();
    // GEMM1: [32 x 512] @ [512 x 256]; wave w -> nt16 = 2w,2w+1
    const unsigned short* p1 = wsu + (size_t)OFF_PNW1 * 2 + (size_t)lp * 131072;
    f32x4 acc[2][2] = {};
    for (int ks = 0; ks < 16; ks++) {
        bf16x8 a0 = *(const bf16x8*)&s_in[l15][ks * 32 + g * 8];
        bf16x8 a1 = *(const bf16x8*)&s_in[16 + l15][ks * 32 + g * 8];
#pragma unroll
        for (int q = 0; q < 2; q++) {
            bf16x8 bf = *(const bf16x8*)&p1[((size_t)(ks * 16 + 2 * w + q) * 64 + ln) * 8];
            acc[0][q] = __builtin_amdgcn_mfma_f32_16x16x32_bf16(a0, bf, acc[0][q], 0, 0, 0);
            acc[1][q] = __builtin_amdgcn_mfma_f32_16x16x32_bf16(a1, bf, acc[1][q], 0, 0, 0);
        }
    }
#pragma unroll
    for (int q = 0; q < 2; q++) {
        int col = w * 32 + q * 16 + l15;
        float b1 = nb1[lp * 256 + col];
#pragma unroll
        for (int mt = 0; mt < 2; mt++)
#pragma unroll
            for (int r = 0; r < 4; r++) s_h[mt * 16 + 4 * g + r][col] = f2bf(silu_f(acc[mt][q][r] + b1));
    }
    __syncthreads();
    // GEMM2: [32 x 256] @ [256 x 256]
    const unsigned short* p2 = wsu + (size_t)OFF_PNW2 * 2 + (size_t)lp * 65536;
    f32x4 a2[2][2] = {};
    for (int ks = 0; ks < 8; ks++) {
        bf16x8 a0 = *(const bf16x8*)&s_h[l15][ks * 32 + g * 8];
        bf16x8 a1 = *(const bf16x8*)&s_h[16 + l15][ks * 32 + g * 8];
#pragma unroll
        for (int q = 0; q < 2; q++) {
            bf16x8 bf = *(const bf16x8*)&p2[((size_t)(ks * 16 + 2 * w + q) * 64 + ln) * 8];
            a2[0][q] = __builtin_amdgcn_mfma_f32_16x16x32_bf16(a0, bf, a2[0][q], 0, 0, 0);
            a2[1][q] = __builtin_amdgcn_mfma_f32_16x16x32_bf16(a1, bf, a2[1][q], 0, 0, 0);
        }
    }
    // read residuals before aliasing s_in
    float res[2][2][4];
#pragma unroll
    for (int q = 0; q < 2; q++) {
        int col = w * 32 + q * 16 + l15;
#pragma unroll
        for (int mt = 0; mt < 2; mt++)
#pragma unroll
            for (int r = 0; r < 4; r++) res[mt][q][r] = bf2f(s_in[mt * 16 + 4 * g + r][col]);
    }
    __syncthreads();   // all s_in / s_h reads done; aliases become writable
#pragma unroll
    for (int q = 0; q < 2; q++) {
        int col = w * 32 + q * 16 + l15;
        float b2 = nb2[lp * 256 + col];
#pragma unroll
        for (int mt = 0; mt < 2; mt++)
#pragma unroll
            for (int r = 0; r < 4; r++) {
                int row = mt * 16 + 4 * g + r;
                float v = res[mt][q][r] + silu_f(a2[mt][q][r] + b2);
                if (row < 24) {
                    s_nf[row][col] = v;
                    out[OUT_NF + (size_t)(n0 + row) * 256 + col] = v;
                }
                s_a[row][col] = f2bf(v);
            }
    }
    __syncthreads();
    // types GEMM: [32 x 256] @ [256 x 112] — waves 0..6
    if (w < 7) {
        const unsigned short* pt = wsu + (size_t)OFF_PWTYPE * 2;
        f32x4 at2[2] = {};
        for (int ks = 0; ks < 8; ks++) {
            bf16x8 a0 = *(const bf16x8*)&s_a[l15][ks * 32 + g * 8];
            bf16x8 a1 = *(const bf16x8*)&s_a[16 + l15][ks * 32 + g * 8];
            bf16x8 bf = *(const bf16x8*)&pt[((size_t)(ks * 7 + w) * 64 + ln) * 8];
            at2[0] = __builtin_amdgcn_mfma_f32_16x16x32_bf16(a0, bf, at2[0], 0, 0, 0);
            at2[1] = __builtin_amdgcn_mfma_f32_16x16x32_bf16(a1, bf, at2[1], 0, 0, 0);
        }
        int a_col = w * 16 + l15;
        if (a_col < 103) {
            float bt = b_type[a_col];
#pragma unroll
            for (int mt = 0; mt < 2; mt++)
#pragma unroll
                for (int r = 0; r < 4; r++) {
                    int row = mt * 16 + 4 * g + r;
                    if (row < 24)
                        out[OUT_TYPES + (size_t)(n0 + row) * 103 + a_col] = at2[mt][r] + bt;
                }
        }
    }
    // coords: 24x3 dots over K=256
    if (tid < 72) {
        int p = tid / 3, cc = tid % 3;
        float a0 = 0.f;
        for (int k = 0; k < 256; k++) a0 += s_nf[p][k] * w_coord[cc * 256 + k];
        out[OUT_COORD + (size_t)(n0 + p) * 3 + cc] = a0;
    }
    // gfeat mean
    if (tid < 256) {
        float s = 0.f;
#pragma unroll
        for (int i = 0; i < 24; i++) s += s_nf[i][tid];
        gf[tid] = s * (1.0f / 24.0f);
    }
    __syncthreads();
    if (tid < 9) {
        float a0 = 0.f;
        for (int k = 0; k < 256; k++) a0 += gf[k] * w_latt[tid * 256 + k];
        lo[tid] = a0;
    }
    __syncthreads();
    if (tid < 9) {
        int i = tid / 3, kk = tid % 3;
        float a0 = 0.f;
#pragma unroll
        for (int j = 0; j < 3; j++) a0 += lo[i * 3 + j] * lattices[b * 9 + j * 3 + kk];
        out[OUT_LATT + (size_t)b * 9 + tid] = a0;
    }
}

extern "C" void kernel_launch(void* const* d_in, const int* in_sizes, int n_in,
                              void* d_out, int out_size, void* d_ws, size_t ws_size,
                              hipStream_t stream) {
    const float* atom_types = (const float*)d_in[0];
    const float* frac       = (const float*)d_in[1];
    const float* lattices   = (const float*)d_in[2];
    const float* t_in       = (const float*)d_in[3];
    const float* text       = (const float*)d_in[4];
    const float* w_emb      = (const float*)d_in[5];
    const float* b_emb      = (const float*)d_in[6];
    const float* w_cond     = (const float*)d_in[7];
    const float* b_cond     = (const float*)d_in[8];
    const float* w_proj     = (const float*)d_in[9];
    const float* b_proj     = (const float*)d_in[10];
    const float* film_g     = (const float*)d_in[11];
    const float* film_b     = (const float*)d_in[12];
    const float* ew1        = (const float*)d_in[13];
    const float* eb1        = (const float*)d_in[14];
    const float* ew2        = (const float*)d_in[15];
    const float* eb2        = (const float*)d_in[16];
    const float* nw1        = (const float*)d_in[17];
    const float* nb1        = (const float*)d_in[18];
    const float* nw2        = (const float*)d_in[19];
    const float* nb2        = (const float*)d_in[20];
    const float* w_coord    = (const float*)d_in[21];
    const float* w_latt     = (const float*)d_in[22];
    const float* w_type     = (const float*)d_in[23];
    const float* b_type     = (const float*)d_in[24];
    float* ws  = (float*)d_ws;
    float* out = (float*)d_out;

    k_prep<<<7700, 256, 0, stream>>>(w_emb, w_cond, w_proj, ew1, ew2, nw1, nw2, w_type, ws);
    k_setup<<<8, 256, 0, stream>>>(lattices, t_in, text, b_cond, ws);
    for (int l = 0; l < NLAYERS; l++) {
        k_fnf<<<N_ / 16, 512, 0, stream>>>(l, atom_types, b_emb, nb1, nb2,
                                           b_proj, film_g, film_b, eb1, ws);
        k_edge<<<N_ * 12 / 24, 256, 0, stream>>>(l, frac, eb2, ws);
    }
    k_tail<<<B_, 512, 0, stream>>>(nb1, nb2, b_type, w_coord, lattices, w_latt, ws, out);
}

// Round 12
// 348.499 us; speedup vs baseline: 1.1993x; 1.0934x over previous
//
#include <hip/hip_runtime.h>
#include <math.h>

// ---- problem constants ----
#define B_      128
#define A_      24
#define N_      3072     // B_*A_
#define NLAYERS 4

// ---- workspace layout (float-element offsets) ----
// NOTE: each [3072][256] bf16 buffer = 786432 ushorts = 393216 float slots.
#define OFF_COND    0         // [128][512] f32                      (65536)
#define OFF_LATW    65536     // [4][128][256] f32                   (131072)
#define OFF_NFMIDH  196608    // [3072][256] bf16                    (393216)
#define OFF_AGGH    589824    // [3072][256] bf16                    (393216)
#define OFF_PARTIH  983040    // [3072][256] bf16 (incl. eb1+latW)   (393216)
#define OFF_PARTJH  1376256   // [3072][256] bf16                    (393216)
#define OFF_W1LATT  1769472   // [4][9][256] f32                     (9216)
#define OFF_PW1A    1778688   // [4][8][16][64][8] bf16              (131072)
#define OFF_PW1B    1909760   //                                     (131072)
#define OFF_PW1D    2040832   // [4][2][16][64][8] bf16              (32768)
#define OFF_PW2     2073600   // [4][8][16][64][8] bf16              (131072)
#define OFF_PWPROJ  2204672   // [8][16][64][8] bf16                 (32768)
#define OFF_PNW1    2237440   // [4][16][16][64][8] bf16             (262144)
#define OFF_PNW2    2499584   // [4][8][16][64][8] bf16              (131072)
#define OFF_PWEMB   2630656   // [4 ks][16 nt][64][8] bf16 (K pad)   (16384)
#define OFF_PWCOND  2647040   // [12 ks][32 nt][64][8] bf16 (K=384)  (98304)
#define OFF_PWTYPE  2745344   // [8 ks][7 nt][64][8] bf16 (N pad)    (14336)
// end 2759680 floats ~ 10.5 MiB

// output offsets (floats): types | lattice | coords | nf
#define OUT_TYPES  0
#define OUT_LATT   316416
#define OUT_COORD  317568
#define OUT_NF     326784

typedef __attribute__((ext_vector_type(8))) short bf16x8;
typedef __attribute__((ext_vector_type(4))) float f32x4;

__device__ __forceinline__ float silu_f(float x) { return x / (1.0f + __expf(-x)); }
__device__ __forceinline__ unsigned short f2bf(float x) {
    unsigned int u = __float_as_uint(x);
    return (unsigned short)((u + 0x7FFFu + ((u >> 16) & 1u)) >> 16);
}
__device__ __forceinline__ float bf2f(unsigned short h) {
    return __uint_as_float(((unsigned int)h) << 16);
}

// ---------------- weight packs ----------------
// generic pack: pack[((ks*NT + nt)*64 + lane)*8 + j] = W[k][n],
//   k = ks*32 + (lane>>4)*8 + j,  n = nt*16 + (lane&15)
__global__ void k_prep(const float* w_emb, const float* w_cond, const float* w_proj,
                       const float* ew1, const float* ew2, const float* nw1, const float* nw2,
                       const float* w_type, float* ws) {
    int idx = blockIdx.x * blockDim.x + threadIdx.x;
    unsigned short* pu = (unsigned short*)ws;
    int i = idx;
    if (i < 9216)   { int l = i / 2304, r = (i % 2304) / 256, h = i % 256;
                      ws[OFF_W1LATT + i] = ew1[((size_t)l * 256 + h) * 581 + 512 + r]; return; }        i -= 9216;
    if (i < 262144) { int l = i >> 16, r = i & 65535, ks = r >> 13, r2 = r & 8191,
                      nt = r2 >> 9, r3 = r2 & 511, lane = r3 >> 3, j = r3 & 7;
                      int k = ks * 32 + (lane >> 4) * 8 + j, n = nt * 16 + (lane & 15);
                      pu[(size_t)OFF_PW1A * 2 + i] = f2bf(ew1[((size_t)l * 256 + n) * 581 + k]); return; } i -= 262144;
    if (i < 262144) { int l = i >> 16, r = i & 65535, ks = r >> 13, r2 = r & 8191,
                      nt = r2 >> 9, r3 = r2 & 511, lane = r3 >> 3, j = r3 & 7;
                      int k = ks * 32 + (lane >> 4) * 8 + j, n = nt * 16 + (lane & 15);
                      pu[(size_t)OFF_PW1B * 2 + i] = f2bf(ew1[((size_t)l * 256 + n) * 581 + 256 + k]); return; } i -= 262144;
    if (i < 65536)  { int l = i >> 14, r = i & 16383, ks = r >> 13, r2 = r & 8191,
                      nt = r2 >> 9, r3 = r2 & 511, lane = r3 >> 3, j = r3 & 7;
                      int kp = ks * 32 + (lane >> 4) * 8 + j, n = nt * 16 + (lane & 15);
                      float v = (kp < 60) ? ew1[((size_t)l * 256 + n) * 581 + 521 + kp] : 0.0f;
                      pu[(size_t)OFF_PW1D * 2 + i] = f2bf(v); return; }                                  i -= 65536;
    if (i < 262144) { int l = i >> 16, r = i & 65535, ks = r >> 13, r2 = r & 8191,
                      nt = r2 >> 9, r3 = r2 & 511, lane = r3 >> 3, j = r3 & 7;
                      int k = ks * 32 + (lane >> 4) * 8 + j, n = nt * 16 + (lane & 15);
                      pu[(size_t)OFF_PW2 * 2 + i] = f2bf(ew2[((size_t)l * 256 + n) * 256 + k]); return; } i -= 262144;
    if (i < 65536)  { int ks = i >> 13, r2 = i & 8191,
                      nt = r2 >> 9, r3 = r2 & 511, lane = r3 >> 3, j = r3 & 7;
                      int k = ks * 32 + (lane >> 4) * 8 + j, n = nt * 16 + (lane & 15);
                      pu[(size_t)OFF_PWPROJ * 2 + i] = f2bf(w_proj[(size_t)n * 256 + k]); return; }      i -= 65536;
    if (i < 524288) { int l = i >> 17, r = i & 131071, ks = r >> 13, r2 = r & 8191,
                      nt = r2 >> 9, r3 = r2 & 511, lane = r3 >> 3, j = r3 & 7;
                      int k = ks * 32 + (lane >> 4) * 8 + j, n = nt * 16 + (lane & 15);
                      pu[(size_t)OFF_PNW1 * 2 + i] = f2bf(nw1[((size_t)l * 256 + n) * 512 + k]); return; } i -= 524288;
    if (i < 262144) { int l = i >> 16, r = i & 65535, ks = r >> 13, r2 = r & 8191,
                      nt = r2 >> 9, r3 = r2 & 511, lane = r3 >> 3, j = r3 & 7;
                      int k = ks * 32 + (lane >> 4) * 8 + j, n = nt * 16 + (lane & 15);
                      pu[(size_t)OFF_PNW2 * 2 + i] = f2bf(nw2[((size_t)l * 256 + n) * 256 + k]); return; } i -= 262144;
    if (i < 32768)  { int ks = i >> 13, r2 = i & 8191,
                      nt = r2 >> 9, r3 = r2 & 511, lane = r3 >> 3, j = r3 & 7;
                      int k = ks * 32 + (lane >> 4) * 8 + j, n = nt * 16 + (lane & 15);
                      float v = (k < 103) ? w_emb[(size_t)n * 103 + k] : 0.0f;
                      pu[(size_t)OFF_PWEMB * 2 + i] = f2bf(v); return; }                                 i -= 32768;
    if (i < 196608) { int ks = i / 16384, r2 = i & 16383,
                      nt = r2 >> 9, r3 = r2 & 511, lane = r3 >> 3, j = r3 & 7;
                      int k = ks * 32 + (lane >> 4) * 8 + j, n = nt * 16 + (lane & 15);
                      pu[(size_t)OFF_PWCOND * 2 + i] = f2bf(w_cond[(size_t)n * 384 + k]); return; }      i -= 196608;
    { int ks = i / 3584, r2 = i % 3584,
      nt = r2 >> 9, r3 = r2 & 511, lane = r3 >> 3, j = r3 & 7;
      int k = ks * 32 + (lane >> 4) * 8 + j, a = nt * 16 + (lane & 15);
      float v = (a < 103) ? w_type[(size_t)a * 256 + k] : 0.0f;
      pu[(size_t)OFF_PWTYPE * 2 + i] = f2bf(v); }
}

// ---------------- setup: latips + latW + cond (MFMA), 8 blocks x 16 graphs ----------------
__global__ void __launch_bounds__(256) k_setup(const float* lat, const float* t_in, const float* tx,
                                               const float* b_cond, float* ws) {
    __shared__ __align__(16) unsigned short s_ct[16][392];
    __shared__ float s_lat[16][9];
    int tid = threadIdx.x, w = tid >> 6, ln = tid & 63;
    int l15 = ln & 15, g = ln >> 4;
    int g0 = blockIdx.x * 16;
    if (tid < 144) {
        int gl = tid / 9, r = tid % 9, ii = r / 3, kk = r % 3;
        const float* L = lat + (g0 + gl) * 9;
        s_lat[gl][r] = L[ii*3+0]*L[kk*3+0] + L[ii*3+1]*L[kk*3+1] + L[ii*3+2]*L[kk*3+2];
    }
    for (int idx = tid; idx < 16 * 384; idx += 256) {
        int row = idx / 384, k = idx % 384;
        float v = (k < 256) ? t_in[(size_t)(g0 + row) * 256 + k] : tx[(size_t)(g0 + row) * 128 + (k - 256)];
        s_ct[row][k] = f2bf(v);
    }
    __syncthreads();
    for (int idx = tid; idx < 16384; idx += 256) {
        int l = idx >> 12, gl = (idx >> 8) & 15, h = idx & 255;
        float a = 0.f;
#pragma unroll
        for (int r = 0; r < 9; r++) a += s_lat[gl][r] * ws[OFF_W1LATT + (l * 9 + r) * 256 + h];
        ws[OFF_LATW + (size_t)(l * 128 + g0 + gl) * 256 + h] = a;
    }
    const unsigned short* pc = (const unsigned short*)ws + (size_t)OFF_PWCOND * 2;
    f32x4 acc[8] = {};
    for (int ks = 0; ks < 12; ks++) {
        bf16x8 a = *(const bf16x8*)&s_ct[l15][ks * 32 + g * 8];
#pragma unroll
        for (int q = 0; q < 8; q++) {
            int nt = w * 8 + q;
            bf16x8 bf = *(const bf16x8*)&pc[((size_t)(ks * 32 + nt) * 64 + ln) * 8];
            acc[q] = __builtin_amdgcn_mfma_f32_16x16x32_bf16(a, bf, acc[q], 0, 0, 0);
        }
    }
#pragma unroll
    for (int q = 0; q < 8; q++) {
        int col = w * 128 + q * 16 + l15;
        float bc = b_cond[col];
#pragma unroll
        for (int r = 0; r < 4; r++) {
            int gg = g0 + 4 * g + r;
            ws[OFF_COND + (size_t)gg * 512 + col] = silu_f(acc[q][r] + bc);
        }
    }
}

// ---------------- fused node-MLP(l-1) [or embed] + FiLM(l) + PartI/PartJ(l) ----------------
// 512 threads / 8 waves; wave w owns N-tiles nt16 = 2w, 2w+1 (cols 32w..32w+31)
__global__ void __launch_bounds__(512) k_fnf(int l, const float* at, const float* b_emb,
                                             const float* nb1, const float* nb2,
                                             const float* b_proj, const float* film_g, const float* film_b,
                                             const float* eb1, float* ws) {
    __shared__ __align__(16) unsigned short s_in[16][536];
    __shared__ __align__(16) unsigned short s_h[16][264];
    __shared__ __align__(16) unsigned short s_a[16][264];
    __shared__ float s_nf[16][260];
    __shared__ float s_mu[16], s_rs[16];
    float (*s_c)[268] = (float(*)[268])&s_in[0][0];   // aliased over s_in (used after node phase)
    int tid = threadIdx.x, w = tid >> 6, ln = tid & 63;
    int l15 = ln & 15, g = ln >> 4;
    int n0 = blockIdx.x * 16;
    const unsigned short* wsu = (const unsigned short*)ws;
    unsigned short* wsw = (unsigned short*)ws;

    f32x4 accn[2] = {};
    if (l == 0) {
        // ---- embed: nf = at @ w_emb^T + b_emb ----
        for (int idx = tid; idx < 16 * 128; idx += 512) {
            int row = idx >> 7, k = idx & 127;
            s_in[row][k] = (k < 103) ? f2bf(at[(size_t)(n0 + row) * 103 + k]) : (unsigned short)0;
        }
        __syncthreads();
        const unsigned short* pe = wsu + (size_t)OFF_PWEMB * 2;
        for (int ks = 0; ks < 4; ks++) {
            bf16x8 a = *(const bf16x8*)&s_in[l15][ks * 32 + g * 8];
#pragma unroll
            for (int q = 0; q < 2; q++) {
                bf16x8 bf = *(const bf16x8*)&pe[((size_t)(ks * 16 + 2 * w + q) * 64 + ln) * 8];
                accn[q] = __builtin_amdgcn_mfma_f32_16x16x32_bf16(a, bf, accn[q], 0, 0, 0);
            }
        }
        __syncthreads();
#pragma unroll
        for (int q = 0; q < 2; q++) {
            int col = w * 32 + q * 16 + l15;
            float be = b_emb[col];
#pragma unroll
            for (int r = 0; r < 4; r++) {
                int row = 4 * g + r;
                float v = accn[q][r] + be;
                s_nf[row][col] = v;
                s_a[row][col] = f2bf(v);
            }
        }
    } else {
        // ---- node MLP of layer l-1 ----
        int lp = l - 1;
        const unsigned short* nfmidh = wsu + (size_t)OFF_NFMIDH * 2;
        const unsigned short* aggh   = wsu + (size_t)OFF_AGGH * 2;
        {
            int row = tid >> 5, c8 = tid & 31;
            *(uint4*)&s_in[row][c8 * 8]       = *(const uint4*)&nfmidh[(size_t)(n0 + row) * 256 + c8 * 8];
            *(uint4*)&s_in[row][256 + c8 * 8] = *(const uint4*)&aggh[(size_t)(n0 + row) * 256 + c8 * 8];
        }
        __syncthreads();
        const unsigned short* p1 = wsu + (size_t)OFF_PNW1 * 2 + (size_t)lp * 131072;
        f32x4 acc[2] = {};
        for (int ks = 0; ks < 16; ks++) {
            bf16x8 a = *(const bf16x8*)&s_in[l15][ks * 32 + g * 8];
#pragma unroll
            for (int q = 0; q < 2; q++) {
                bf16x8 bf = *(const bf16x8*)&p1[((size_t)(ks * 16 + 2 * w + q) * 64 + ln) * 8];
                acc[q] = __builtin_amdgcn_mfma_f32_16x16x32_bf16(a, bf, acc[q], 0, 0, 0);
            }
        }
#pragma unroll
        for (int q = 0; q < 2; q++) {
            int col = w * 32 + q * 16 + l15;
            float b1 = nb1[lp * 256 + col];
#pragma unroll
            for (int r = 0; r < 4; r++) s_h[4 * g + r][col] = f2bf(silu_f(acc[q][r] + b1));
        }
        __syncthreads();
        const unsigned short* p2 = wsu + (size_t)OFF_PNW2 * 2 + (size_t)lp * 65536;
        for (int ks = 0; ks < 8; ks++) {
            bf16x8 a = *(const bf16x8*)&s_h[l15][ks * 32 + g * 8];
#pragma unroll
            for (int q = 0; q < 2; q++) {
                bf16x8 bf = *(const bf16x8*)&p2[((size_t)(ks * 16 + 2 * w + q) * 64 + ln) * 8];
                accn[q] = __builtin_amdgcn_mfma_f32_16x16x32_bf16(a, bf, accn[q], 0, 0, 0);
            }
        }
#pragma unroll
        for (int q = 0; q < 2; q++) {
            int col = w * 32 + q * 16 + l15;
            float b2 = nb2[lp * 256 + col];
#pragma unroll
            for (int r = 0; r < 4; r++) {
                int row = 4 * g + r;
                float v = bf2f(s_in[row][col]) + silu_f(accn[q][r] + b2);
                s_nf[row][col] = v;
                s_a[row][col] = f2bf(v);
            }
        }
    }
    __syncthreads();
    // ---- proj GEMM: [16 x 256] @ [256 x 256] ----
    const unsigned short* pwp = wsu + (size_t)OFF_PWPROJ * 2;
    f32x4 accp[2] = {};
    for (int ks = 0; ks < 8; ks++) {
        bf16x8 a = *(const bf16x8*)&s_a[l15][ks * 32 + g * 8];
#pragma unroll
        for (int q = 0; q < 2; q++) {
            bf16x8 bf = *(const bf16x8*)&pwp[((size_t)(ks * 16 + 2 * w + q) * 64 + ln) * 8];
            accp[q] = __builtin_amdgcn_mfma_f32_16x16x32_bf16(a, bf, accp[q], 0, 0, 0);
        }
    }
    __syncthreads();  // s_in (node phase) fully read; s_c (alias) may be written
#pragma unroll
    for (int q = 0; q < 2; q++) {
        int col = w * 32 + q * 16 + l15;
        float bp = b_proj[col];
#pragma unroll
        for (int r = 0; r < 4; r++) s_c[4 * g + r][col] = accp[q][r] + bp;
    }
    __syncthreads();
    // ---- LN stats: wave w handles rows 2w, 2w+1 ----
    for (int r2 = 0; r2 < 2; r2++) {
        int row = w * 2 + r2;
        float s = 0.f, q = 0.f;
        for (int c = ln; c < 256; c += 64) { float v = s_c[row][c]; s += v; q += v * v; }
#pragma unroll
        for (int o = 1; o < 64; o <<= 1) { s += __shfl_xor(s, o); q += __shfl_xor(q, o); }
        if (ln == 0) {
            float mu = s * (1.0f / 256.0f);
            float var = q * (1.0f / 256.0f) - mu * mu;
            s_mu[row] = mu; s_rs[row] = rsqrtf(var + 1e-5f);
        }
    }
    __syncthreads();
    // ---- FiLM epilogue: col = tid&255, rows (tid>>8) + 2t ----
    {
        int col = tid & 255, rb = tid >> 8;
        float gg = film_g[col], bb = film_b[col];
        unsigned short* nfmidh = wsw + (size_t)OFF_NFMIDH * 2;
#pragma unroll
        for (int t = 0; t < 8; t++) {
            int row = rb + 2 * t;
            int n = n0 + row, b = n / 24;
            float sc = ws[OFF_COND + (size_t)b * 512 + col];
            float sh = ws[OFF_COND + (size_t)b * 512 + 256 + col];
            float yn = (s_c[row][col] - s_mu[row]) * s_rs[row] * gg + bb;
            float outv = s_nf[row][col] + silu_f(yn * sc + sh);
            unsigned short ob = f2bf(outv);
            nfmidh[(size_t)n * 256 + col] = ob;
            s_a[row][col] = ob;
        }
    }
    __syncthreads();
    // ---- PartI/PartJ GEMMs ----
    const unsigned short* pA = wsu + (size_t)OFF_PW1A * 2 + (size_t)l * 65536;
    const unsigned short* pB = wsu + (size_t)OFF_PW1B * 2 + (size_t)l * 65536;
    f32x4 aI[2] = {}, aJ[2] = {};
    for (int ks = 0; ks < 8; ks++) {
        bf16x8 a = *(const bf16x8*)&s_a[l15][ks * 32 + g * 8];
#pragma unroll
        for (int q = 0; q < 2; q++) {
            bf16x8 bi = *(const bf16x8*)&pA[((size_t)(ks * 16 + 2 * w + q) * 64 + ln) * 8];
            bf16x8 bj = *(const bf16x8*)&pB[((size_t)(ks * 16 + 2 * w + q) * 64 + ln) * 8];
            aI[q] = __builtin_amdgcn_mfma_f32_16x16x32_bf16(a, bi, aI[q], 0, 0, 0);
            aJ[q] = __builtin_amdgcn_mfma_f32_16x16x32_bf16(a, bj, aJ[q], 0, 0, 0);
        }
    }
    unsigned short* partih = wsw + (size_t)OFF_PARTIH * 2;
    unsigned short* partjh = wsw + (size_t)OFF_PARTJH * 2;
#pragma unroll
    for (int q = 0; q < 2; q++) {
        int col = w * 32 + q * 16 + l15;
        float e1 = eb1[l * 256 + col];
#pragma unroll
        for (int r = 0; r < 4; r++) {
            int n = n0 + 4 * g + r;
            int gb = n / 24;
            float vi = aI[q][r] + e1 + ws[OFF_LATW + (size_t)(l * 128 + gb) * 256 + col];
            partih[(size_t)n * 256 + col] = f2bf(vi);
            partjh[(size_t)n * 256 + col] = f2bf(aJ[q][r]);
        }
    }
}

// ---------------- fused edge pipeline (C-seed adds; pJ/demb packed in ef1 buffer; 5 blocks/CU) ----------------
// s_u phases: [0,6336) pJ stage | [6336,12480) demb | after both consumed: [0,12288) ef1
#define SU_WORDS 12480
#define DOFF     6336
__global__ void __launch_bounds__(256, 5) k_edge(int l, const float* frac, const float* eb2, float* ws) {
    __shared__ __align__(16) unsigned short s_u[SU_WORDS];
    __shared__ __align__(16) unsigned short s_pI[2][264];
    __shared__ float s_fc[24][3];
    int tid = threadIdx.x, w = tid >> 6, ln = tid & 63;
    int l15 = ln & 15, g = ln >> 4;
    int b = blockIdx.x & 127, c = blockIdx.x >> 7;
    int i0 = c * 2, n0i = b * 24;
    const unsigned short* wsu = (const unsigned short*)ws;

    // ---- phase 1: stage fc, pJ (coalesced into s_u[0..6336)), pI ----
    const unsigned short* partjh = wsu + (size_t)OFF_PARTJH * 2 + (size_t)n0i * 256;
    const unsigned short* partih = wsu + (size_t)OFF_PARTIH * 2 + (size_t)(n0i + i0) * 256;
    for (int idx = tid; idx < 72; idx += 256) s_fc[idx / 3][idx % 3] = frac[b * 72 + idx];
    for (int idx = tid; idx < 768; idx += 256) {
        int row = idx >> 5, c8 = idx & 31;
        *(uint4*)&s_u[row * 264 + c8 * 8] = *(const uint4*)&partjh[row * 256 + c8 * 8];
    }
    if (tid < 64) {
        int row = tid >> 5, c8 = tid & 31;
        *(uint4*)&s_pI[row][c8 * 8] = *(const uint4*)&partih[row * 256 + c8 * 8];
    }
    __syncthreads();
    // ---- phase 2: seed acc = pI + pJ (C-in for GEMM1); write demb to [DOFF..) ----
    float pIv[2][4];
#pragma unroll
    for (int hi = 0; hi < 2; hi++)
#pragma unroll
        for (int nt = 0; nt < 4; nt++) pIv[hi][nt] = bf2f(s_pI[hi][w * 64 + nt * 16 + l15]);
    f32x4 acc[3][4];
#pragma unroll
    for (int mt = 0; mt < 3; mt++)
#pragma unroll
        for (int nt = 0; nt < 4; nt++) {
            int col = w * 64 + nt * 16 + l15;
#pragma unroll
            for (int r = 0; r < 4; r++) {
                int row = mt * 16 + 4 * g + r;
                int hi = (row >= 24);
                int j = row - 24 * hi;
                acc[mt][nt][r] = pIv[hi][nt] + bf2f(s_u[j * 264 + col]);
            }
        }
    for (int idx = tid; idx < 3072; idx += 256) {
        int row = idx >> 6, k = idx & 63;
        unsigned short v = 0;
        if (k < 60) {
            int kk = (k < 30) ? k : k - 30;
            int d = kk / 10, f = kk % 10;
            int hi = (row >= 24);
            int j = row - (hi ? 24 : 0);
            float fd = s_fc[j][d] - s_fc[i0 + hi][d];
            fd -= floorf(fd);
            float ang = fd * (6.283185307179586f * (float)f);
            v = f2bf((k < 30) ? __sinf(ang) : __cosf(ang));
        }
        s_u[DOFF + (row << 6) + (((k >> 3) ^ (row & 7)) << 3) + (k & 7)] = v;
    }
    __syncthreads();
    // ---- GEMM1: [48 x 64] @ [64 x 256], accumulating on seeded C ----
    const unsigned short* pw1d = wsu + (size_t)OFF_PW1D * 2 + (size_t)l * 16384;
    for (int ks = 0; ks < 2; ks++) {
        bf16x8 a[3];
        int kb = ks * 4 + g;
#pragma unroll
        for (int mt = 0; mt < 3; mt++) {
            int row = mt * 16 + l15;
            a[mt] = *(const bf16x8*)&s_u[DOFF + (row << 6) + ((kb ^ (row & 7)) << 3)];
        }
#pragma unroll
        for (int nt = 0; nt < 4; nt++) {
            bf16x8 bf = *(const bf16x8*)&pw1d[((size_t)(ks * 16 + w * 4 + nt) * 64 + ln) * 8];
#pragma unroll
            for (int mt = 0; mt < 3; mt++)
                acc[mt][nt] = __builtin_amdgcn_mfma_f32_16x16x32_bf16(a[mt], bf, acc[mt][nt], 0, 0, 0);
        }
    }
    __syncthreads();   // all pJ/demb reads done; ef1 may overwrite s_u
    // ---- epilogue: ef1 = silu(acc), swizzled ----
#pragma unroll
    for (int mt = 0; mt < 3; mt++)
#pragma unroll
        for (int nt = 0; nt < 4; nt++) {
            int col = w * 64 + nt * 16 + l15;
#pragma unroll
            for (int r = 0; r < 4; r++) {
                int row = mt * 16 + 4 * g + r;
                s_u[(row << 8) + ((((col >> 3) ^ (row & 7))) << 3) + (col & 7)] = f2bf(silu_f(acc[mt][nt][r]));
            }
        }
    __syncthreads();
    // ---- GEMM2: [48 x 256] @ [256 x 256] ----
    const unsigned short* pw2 = wsu + (size_t)OFF_PW2 * 2 + (size_t)l * 65536;
    f32x4 acc2[3][4] = {};
    for (int ks = 0; ks < 8; ks++) {
        bf16x8 a[3];
        int kb = ks * 4 + g;
#pragma unroll
        for (int mt = 0; mt < 3; mt++) {
            int row = mt * 16 + l15;
            a[mt] = *(const bf16x8*)&s_u[(row << 8) + ((kb ^ (row & 7)) << 3)];
        }
#pragma unroll
        for (int nt = 0; nt < 4; nt++) {
            bf16x8 bf = *(const bf16x8*)&pw2[((size_t)(ks * 16 + w * 4 + nt) * 64 + ln) * 8];
#pragma unroll
            for (int mt = 0; mt < 3; mt++)
                acc2[mt][nt] = __builtin_amdgcn_mfma_f32_16x16x32_bf16(a[mt], bf, acc2[mt][nt], 0, 0, 0);
        }
    }
    // ---- in-register silu + aggregation over 24 edges per i-group ----
    float s0[4] = {}, s1[4] = {};
#pragma unroll
    for (int nt = 0; nt < 4; nt++) {
        int col = w * 64 + nt * 16 + l15;
        float b2 = eb2[l * 256 + col];
#pragma unroll
        for (int r = 0; r < 4; r++) s0[nt] += silu_f(acc2[0][nt][r] + b2);
        float m = 0.f;
#pragma unroll
        for (int r = 0; r < 4; r++) m += silu_f(acc2[1][nt][r] + b2);
        if (g < 2) s0[nt] += m; else s1[nt] += m;
#pragma unroll
        for (int r = 0; r < 4; r++) s1[nt] += silu_f(acc2[2][nt][r] + b2);
    }
#pragma unroll
    for (int nt = 0; nt < 4; nt++) {
        s0[nt] += __shfl_xor(s0[nt], 16);
        s0[nt] += __shfl_xor(s0[nt], 32);
        s1[nt] += __shfl_xor(s1[nt], 16);
        s1[nt] += __shfl_xor(s1[nt], 32);
    }
    unsigned short* aggh = (unsigned short*)ws + (size_t)OFF_AGGH * 2;
    if (g == 0) {
#pragma unroll
        for (int nt = 0; nt < 4; nt++) {
            int col = w * 64 + nt * 16 + l15;
            aggh[(size_t)(n0i + i0) * 256 + col]     = f2bf(s0[nt] * (1.0f / 24.0f));
            aggh[(size_t)(n0i + i0 + 1) * 256 + col] = f2bf(s1[nt] * (1.0f / 24.0f));
        }
    }
}

// ---------------- tail: node-MLP(3) + types + coords + nf-out + lattice, graph-aligned ----------------
// 128 blocks x 512 threads; 24 real rows padded to M=32 (pad rows' outputs discarded)
__global__ void __launch_bounds__(512) k_tail(const float* nb1, const float* nb2,
                                              const float* b_type, const float* w_coord,
                                              const float* lattices, const float* w_latt,
                                              float* ws, float* out) {
    __shared__ __align__(16) unsigned short s_in[32][536];
    __shared__ __align__(16) unsigned short s_h[32][264];
    __shared__ float gf[256];
    __shared__ float lo[9];
    float (*s_nf)[260] = (float(*)[260])&s_in[0][0];       // alias: valid after residual reads
    unsigned short (*s_a)[264] = s_h;                       // alias: valid after GEMM2 reads
    int tid = threadIdx.x, w = tid >> 6, ln = tid & 63;
    int l15 = ln & 15, g = ln >> 4;
    int b = blockIdx.x, n0 = b * 24;
    const unsigned short* wsu = (const unsigned short*)ws;
    const int lp = 3;
    const unsigned short* nfmidh = wsu + (size_t)OFF_NFMIDH * 2;
    const unsigned short* aggh   = wsu + (size_t)OFF_AGGH * 2;
    for (int idx = tid; idx < 1024; idx += 512) {
        int row = idx >> 5, c8 = idx & 31;
        int rr = (row < 24) ? row : 0;
        *(uint4*)&s_in[row][c8 * 8]       = *(const uint4*)&nfmidh[(size_t)(n0 + rr) * 256 + c8 * 8];
        *(uint4*)&s_in[row][256 + c8 * 8] = *(const uint4*)&aggh[(size_t)(n0 + rr) * 256 + c8 * 8];
    }
    __syncthreads();
    // GEMM1: [32 x 512] @ [512 x 256]; wave w -> nt16 = 2w,2w+1
    const unsigned short* p1 = wsu + (size_t)OFF_PNW1 * 2 + (size_t)lp * 131072;
    f32x4 acc[2][2] = {};
    for (int ks = 0; ks < 16; ks++) {
        bf16x8 a0 = *(const bf16x8*)&s_in[l15][ks * 32 + g * 8];
        bf16x8 a1 = *(const bf16x8*)&s_in[16 + l15][ks * 32 + g * 8];
#pragma unroll
        for (int q = 0; q < 2; q++) {
            bf16x8 bf = *(const bf16x8*)&p1[((size_t)(ks * 16 + 2 * w + q) * 64 + ln) * 8];
            acc[0][q] = __builtin_amdgcn_mfma_f32_16x16x32_bf16(a0, bf, acc[0][q], 0, 0, 0);
            acc[1][q] = __builtin_amdgcn_mfma_f32_16x16x32_bf16(a1, bf, acc[1][q], 0, 0, 0);
        }
    }
#pragma unroll
    for (int q = 0; q < 2; q++) {
        int col = w * 32 + q * 16 + l15;
        float b1 = nb1[lp * 256 + col];
#pragma unroll
        for (int mt = 0; mt < 2; mt++)
#pragma unroll
            for (int r = 0; r < 4; r++) s_h[mt * 16 + 4 * g + r][col] = f2bf(silu_f(acc[mt][q][r] + b1));
    }
    __syncthreads();
    // GEMM2: [32 x 256] @ [256 x 256]
    const unsigned short* p2 = wsu + (size_t)OFF_PNW2 * 2 + (size_t)lp * 65536;
    f32x4 a2[2][2] = {};
    for (int ks = 0; ks < 8; ks++) {
        bf16x8 a0 = *(const bf16x8*)&s_h[l15][ks * 32 + g * 8];
        bf16x8 a1 = *(const bf16x8*)&s_h[16 + l15][ks * 32 + g * 8];
#pragma unroll
        for (int q = 0; q < 2; q++) {
            bf16x8 bf = *(const bf16x8*)&p2[((size_t)(ks * 16 + 2 * w + q) * 64 + ln) * 8];
            a2[0][q] = __builtin_amdgcn_mfma_f32_16x16x32_bf16(a0, bf, a2[0][q], 0, 0, 0);
            a2[1][q] = __builtin_amdgcn_mfma_f32_16x16x32_bf16(a1, bf, a2[1][q], 0, 0, 0);
        }
    }
    // read residuals before aliasing s_in
    float res[2][2][4];
#pragma unroll
    for (int q = 0; q < 2; q++) {
        int col = w * 32 + q * 16 + l15;
#pragma unroll
        for (int mt = 0; mt < 2; mt++)
#pragma unroll
            for (int r = 0; r < 4; r++) res[mt][q][r] = bf2f(s_in[mt * 16 + 4 * g + r][col]);
    }
    __syncthreads();   // all s_in / s_h reads done; aliases become writable
#pragma unroll
    for (int q = 0; q < 2; q++) {
        int col = w * 32 + q * 16 + l15;
        float b2 = nb2[lp * 256 + col];
#pragma unroll
        for (int mt = 0; mt < 2; mt++)
#pragma unroll
            for (int r = 0; r < 4; r++) {
                int row = mt * 16 + 4 * g + r;
                float v = res[mt][q][r] + silu_f(a2[mt][q][r] + b2);
                if (row < 24) {
                    s_nf[row][col] = v;
                    out[OUT_NF + (size_t)(n0 + row) * 256 + col] = v;
                }
                s_a[row][col] = f2bf(v);
            }
    }
    __syncthreads();
    // types GEMM: [32 x 256] @ [256 x 112] — waves 0..6
    if (w < 7) {
        const unsigned short* pt = wsu + (size_t)OFF_PWTYPE * 2;
        f32x4 at2[2] = {};
        for (int ks = 0; ks < 8; ks++) {
            bf16x8 a0 = *(const bf16x8*)&s_a[l15][ks * 32 + g * 8];
            bf16x8 a1 = *(const bf16x8*)&s_a[16 + l15][ks * 32 + g * 8];
            bf16x8 bf = *(const bf16x8*)&pt[((size_t)(ks * 7 + w) * 64 + ln) * 8];
            at2[0] = __builtin_amdgcn_mfma_f32_16x16x32_bf16(a0, bf, at2[0], 0, 0, 0);
            at2[1] = __builtin_amdgcn_mfma_f32_16x16x32_bf16(a1, bf, at2[1], 0, 0, 0);
        }
        int a_col = w * 16 + l15;
        if (a_col < 103) {
            float bt = b_type[a_col];
#pragma unroll
            for (int mt = 0; mt < 2; mt++)
#pragma unroll
                for (int r = 0; r < 4; r++) {
                    int row = mt * 16 + 4 * g + r;
                    if (row < 24)
                        out[OUT_TYPES + (size_t)(n0 + row) * 103 + a_col] = at2[mt][r] + bt;
                }
        }
    }
    // coords: 24x3 dots over K=256
    if (tid < 72) {
        int p = tid / 3, cc = tid % 3;
        float a0 = 0.f;
        for (int k = 0; k < 256; k++) a0 += s_nf[p][k] * w_coord[cc * 256 + k];
        out[OUT_COORD + (size_t)(n0 + p) * 3 + cc] = a0;
    }
    // gfeat mean
    if (tid < 256) {
        float s = 0.f;
#pragma unroll
        for (int i = 0; i < 24; i++) s += s_nf[i][tid];
        gf[tid] = s * (1.0f / 24.0f);
    }
    __syncthreads();
    if (tid < 9) {
        float a0 = 0.f;
        for (int k = 0; k < 256; k++) a0 += gf[k] * w_latt[tid * 256 + k];
        lo[tid] = a0;
    }
    __syncthreads();
    if (tid < 9) {
        int i = tid / 3, kk = tid % 3;
        float a0 = 0.f;
#pragma unroll
        for (int j = 0; j < 3; j++) a0 += lo[i * 3 + j] * lattices[b * 9 + j * 3 + kk];
        out[OUT_LATT + (size_t)b * 9 + tid] = a0;
    }
}

extern "C" void kernel_launch(void* const* d_in, const int* in_sizes, int n_in,
                              void* d_out, int out_size, void* d_ws, size_t ws_size,
                              hipStream_t stream) {
    const float* atom_types = (const float*)d_in[0];
    const float* frac       = (const float*)d_in[1];
    const float* lattices   = (const float*)d_in[2];
    const float* t_in       = (const float*)d_in[3];
    const float* text       = (const float*)d_in[4];
    const float* w_emb      = (const float*)d_in[5];
    const float* b_emb      = (const float*)d_in[6];
    const float* w_cond     = (const float*)d_in[7];
    const float* b_cond     = (const float*)d_in[8];
    const float* w_proj     = (const float*)d_in[9];
    const float* b_proj     = (const float*)d_in[10];
    const float* film_g     = (const float*)d_in[11];
    const float* film_b     = (const float*)d_in[12];
    const float* ew1        = (const float*)d_in[13];
    const float* eb1        = (const float*)d_in[14];
    const float* ew2        = (const float*)d_in[15];
    const float* eb2        = (const float*)d_in[16];
    const float* nw1        = (const float*)d_in[17];
    const float* nb1        = (const float*)d_in[18];
    const float* nw2        = (const float*)d_in[19];
    const float* nb2        = (const float*)d_in[20];
    const float* w_coord    = (const float*)d_in[21];
    const float* w_latt     = (const float*)d_in[22];
    const float* w_type     = (const float*)d_in[23];
    const float* b_type     = (const float*)d_in[24];
    float* ws  = (float*)d_ws;
    float* out = (float*)d_out;

    k_prep<<<7700, 256, 0, stream>>>(w_emb, w_cond, w_proj, ew1, ew2, nw1, nw2, w_type, ws);
    k_setup<<<8, 256, 0, stream>>>(lattices, t_in, text, b_cond, ws);
    for (int l = 0; l < NLAYERS; l++) {
        k_fnf<<<N_ / 16, 512, 0, stream>>>(l, atom_types, b_emb, nb1, nb2,
                                           b_proj, film_g, film_b, eb1, ws);
        k_edge<<<N_ * 12 / 24, 256, 0, stream>>>(l, frac, eb2, ws);
    }
    k_tail<<<B_, 512, 0, stream>>>(nb1, nb2, b_type, w_coord, lattices, w_latt, ws, out);
}